// Round 9
// baseline (7533.822 us; speedup 1.0000x reference)
//
#include <hip/hip_runtime.h>

// Problem constants
#define B_ 64
#define S_ 64
#define T_ 64
#define V_ 32000
#define D_ 512
#define H_ 1024
#define L_ 256

typedef _Float16 f16;
typedef __attribute__((ext_vector_type(4))) _Float16 f16x4;
typedef __attribute__((ext_vector_type(8))) _Float16 f16x8;
typedef __attribute__((ext_vector_type(16))) float f32x16;

#define INV2048 (1.0f / 2048.0f)

// ---------------------------------------------------------------------------
// f16 hi/lo frag write for h values (A-operand layout, m=b, k=j).
// ---------------------------------------------------------------------------
__device__ __forceinline__ void write_frag(f16* __restrict__ Aohi, f16* __restrict__ Aolo,
                                           int b, int j, float hv) {
  const f16 hi = (f16)hv;
  const f16 lo = (f16)((hv - (float)hi) * 2048.0f);
  const long long fo =
      (((long long)(b >> 5) * 64 + (j >> 4)) * 64 + ((b & 31) + 32 * ((j >> 3) & 1))) * 8 + (j & 7);
  Aohi[fo] = hi;
  Aolo[fo] = lo;
}

__device__ __forceinline__ void cvt8(const float4& v0, const float4& v1, f16x8& hi, f16x8& lo) {
  float vv[8] = {v0.x, v0.y, v0.z, v0.w, v1.x, v1.y, v1.z, v1.w};
#pragma unroll
  for (int e = 0; e < 8; ++e) {
    const f16 h = (f16)vv[e];
    hi[e] = h;
    lo[e] = (f16)((vv[e] - (float)h) * 2048.0f);
  }
}

// ---------------------------------------------------------------------------
// Pack fp32 weights [N][K] into MFMA B-frag-major f16 hi/lo.
// ---------------------------------------------------------------------------
template <int K>
__global__ __launch_bounds__(256) void k_pack_wf(
    const float* __restrict__ W, f16* __restrict__ Bhi, f16* __restrict__ Blo)
{
  const int n = blockIdx.x;
  const int k = threadIdx.x * 4;
  if (k >= K) return;
  float4 w = *reinterpret_cast<const float4*>(W + (long long)n * K + k);
  float wv[4] = {w.x, w.y, w.z, w.w};
  f16x4 hi, lo;
#pragma unroll
  for (int i = 0; i < 4; ++i) {
    const f16 h = (f16)wv[i];
    hi[i] = h;
    lo[i] = (f16)((wv[i] - (float)h) * 2048.0f);
  }
  const int nt = n >> 5;
  const int lane = (n & 31) + 32 * ((k >> 3) & 1);
  const int ks = k >> 4;
  const long long off = (((long long)nt * (K / 16) + ks) * 64 + lane) * 8 + (k & 7);
  *reinterpret_cast<f16x4*>(Bhi + off) = hi;
  *reinterpret_cast<f16x4*>(Blo + off) = lo;
}

// ---------------------------------------------------------------------------
// Pack encoder token embeddings into A-frags (m = s*64+b, K = 512).
// ---------------------------------------------------------------------------
__global__ __launch_bounds__(128) void k_pack_xe(
    const int* __restrict__ x, const float* __restrict__ E,
    f16* __restrict__ XAhi, f16* __restrict__ XAlo)
{
  const int m = blockIdx.x;
  const int s = m >> 6, b = m & 63;
  const int k = threadIdx.x * 4;
  const long long tok = x[b * S_ + s];
  float4 w = *reinterpret_cast<const float4*>(E + tok * D_ + k);
  float wv[4] = {w.x, w.y, w.z, w.w};
  f16x4 hi, lo;
#pragma unroll
  for (int i = 0; i < 4; ++i) {
    const f16 h = (f16)wv[i];
    hi[i] = h;
    lo[i] = (f16)((wv[i] - (float)h) * 2048.0f);
  }
  const int mt = m >> 5;
  const int lane = (m & 31) + 32 * ((k >> 3) & 1);
  const int ks = k >> 4;
  const long long off = (((long long)mt * 32 + ks) * 64 + lane) * 8 + (k & 7);
  *reinterpret_cast<f16x4*>(XAhi + off) = hi;
  *reinterpret_cast<f16x4*>(XAlo + off) = lo;
}

// ---------------------------------------------------------------------------
// Encoder input-gates GEMM (proven kernel).
// ---------------------------------------------------------------------------
__global__ __launch_bounds__(256) void k_gates_mfma(
    const f16* __restrict__ XAhi, const f16* __restrict__ XAlo,
    const f16* __restrict__ Bhi, const f16* __restrict__ Blo,
    const float* __restrict__ b_ih, float* __restrict__ Gi)
{
  __shared__ float cand[4][64][33];
  const int tid = threadIdx.x;
  const int lane = tid & 63;
  const int wv = __builtin_amdgcn_readfirstlane(tid >> 6);
  const int s = blockIdx.x / 24;
  const int ng = blockIdx.x % 24;
  const int nt = ng * 4 + wv;

  f32x16 aM0, aM1, aL0, aL1;
#pragma unroll
  for (int i = 0; i < 16; ++i) { aM0[i] = 0.f; aM1[i] = 0.f; aL0[i] = 0.f; aL1[i] = 0.f; }

  const f16x8* pB_h = reinterpret_cast<const f16x8*>(Bhi) + ((long long)nt * 32) * 64 + lane;
  const f16x8* pB_l = reinterpret_cast<const f16x8*>(Blo) + ((long long)nt * 32) * 64 + lane;
  const f16x8* pA_h = reinterpret_cast<const f16x8*>(XAhi) + ((long long)s * 64) * 64 + lane;
  const f16x8* pA_l = reinterpret_cast<const f16x8*>(XAlo) + ((long long)s * 64) * 64 + lane;

#pragma unroll 4
  for (int ks = 0; ks < 32; ++ks) {
    const int o = ks * 64;
    f16x8 bh = pB_h[o];
    f16x8 bl = pB_l[o];
    f16x8 a0 = pA_h[o];
    f16x8 a1 = pA_h[o + 32 * 64];
    f16x8 l0 = pA_l[o];
    f16x8 l1 = pA_l[o + 32 * 64];
    aM0 = __builtin_amdgcn_mfma_f32_32x32x16_f16(a0, bh, aM0, 0, 0, 0);
    aM1 = __builtin_amdgcn_mfma_f32_32x32x16_f16(a1, bh, aM1, 0, 0, 0);
    aL0 = __builtin_amdgcn_mfma_f32_32x32x16_f16(a0, bl, aL0, 0, 0, 0);
    aL0 = __builtin_amdgcn_mfma_f32_32x32x16_f16(l0, bh, aL0, 0, 0, 0);
    aL1 = __builtin_amdgcn_mfma_f32_32x32x16_f16(a1, bl, aL1, 0, 0, 0);
    aL1 = __builtin_amdgcn_mfma_f32_32x32x16_f16(l1, bh, aL1, 0, 0, 0);
  }

  {
    const int l = lane & 31;
    const int rbase = 4 * (lane >> 5);
#pragma unroll
    for (int reg = 0; reg < 16; ++reg) {
      const int row = (reg & 3) + 8 * (reg >> 2) + rbase;
      cand[wv][row][l] = aM0[reg] + aL0[reg] * INV2048;
      cand[wv][row + 32][l] = aM1[reg] + aL1[reg] * INV2048;
    }
  }
  __syncthreads();
  const int bn0 = ng * 128;
#pragma unroll
  for (int i = 0; i < 8; ++i) {
    const int idx = i * 256 + tid;
    const int b4 = (idx & 15) * 4;
    const int nl = idx >> 4;
    const float bi = b_ih[bn0 + nl];
    float4 o;
    o.x = cand[nl >> 5][b4 + 0][nl & 31] + bi;
    o.y = cand[nl >> 5][b4 + 1][nl & 31] + bi;
    o.z = cand[nl >> 5][b4 + 2][nl & 31] + bi;
    o.w = cand[nl >> 5][b4 + 3][nl & 31] + bi;
    *reinterpret_cast<float4*>(&Gi[((long long)s * (3 * H_) + bn0 + nl) * 64 + b4]) = o;
  }
}

// ---------------------------------------------------------------------------
// hh pre-activations via MFMA (used once for decoder init). grid = 96 x 256.
// ---------------------------------------------------------------------------
__global__ __launch_bounds__(256) void k_hh_mfma(
    const f16* __restrict__ Ahi, const f16* __restrict__ Alo,
    const f16* __restrict__ Bhi, const f16* __restrict__ Blo,
    float* __restrict__ preH)
{
  __shared__ float cand[4][64][33];
  const int tid = threadIdx.x;
  const int lane = tid & 63;
  const int wv = __builtin_amdgcn_readfirstlane(tid >> 6);
  const int nt = blockIdx.x;

  f32x16 aM0, aM1, aL0, aL1;
#pragma unroll
  for (int i = 0; i < 16; ++i) { aM0[i] = 0.f; aM1[i] = 0.f; aL0[i] = 0.f; aL1[i] = 0.f; }

  const f16x8* pB_h = reinterpret_cast<const f16x8*>(Bhi) + ((long long)nt * 64 + wv * 16) * 64 + lane;
  const f16x8* pB_l = reinterpret_cast<const f16x8*>(Blo) + ((long long)nt * 64 + wv * 16) * 64 + lane;
  const f16x8* pA_h = reinterpret_cast<const f16x8*>(Ahi) + (long long)(wv * 16) * 64 + lane;
  const f16x8* pA_l = reinterpret_cast<const f16x8*>(Alo) + (long long)(wv * 16) * 64 + lane;

#pragma unroll 4
  for (int q = 0; q < 16; ++q) {
    const int o = q * 64;
    f16x8 bh = pB_h[o];
    f16x8 bl = pB_l[o];
    f16x8 a0 = pA_h[o];
    f16x8 a1 = pA_h[o + 4096];
    f16x8 l0 = pA_l[o];
    f16x8 l1 = pA_l[o + 4096];
    aM0 = __builtin_amdgcn_mfma_f32_32x32x16_f16(a0, bh, aM0, 0, 0, 0);
    aM1 = __builtin_amdgcn_mfma_f32_32x32x16_f16(a1, bh, aM1, 0, 0, 0);
    aL0 = __builtin_amdgcn_mfma_f32_32x32x16_f16(a0, bl, aL0, 0, 0, 0);
    aL0 = __builtin_amdgcn_mfma_f32_32x32x16_f16(l0, bh, aL0, 0, 0, 0);
    aL1 = __builtin_amdgcn_mfma_f32_32x32x16_f16(a1, bl, aL1, 0, 0, 0);
    aL1 = __builtin_amdgcn_mfma_f32_32x32x16_f16(l1, bh, aL1, 0, 0, 0);
  }

  {
    const int l = lane & 31;
    const int rbase = 4 * (lane >> 5);
#pragma unroll
    for (int reg = 0; reg < 16; ++reg) {
      const int row = (reg & 3) + 8 * (reg >> 2) + rbase;
      cand[wv][row][l] = aM0[reg] + aL0[reg] * INV2048;
      cand[wv][row + 32][l] = aM1[reg] + aL1[reg] * INV2048;
    }
  }
  __syncthreads();
#pragma unroll
  for (int i = 0; i < 8; ++i) {
    const int idx = i * 256 + tid;
    const int b = idx & 63;
    const int l = idx >> 6;
    const float v = cand[0][b][l] + cand[1][b][l] + cand[2][b][l] + cand[3][b][l];
    preH[((long long)nt * 32 + l) * 64 + b] = v;
  }
}

// ---------------------------------------------------------------------------
// Fused encoder step (col-slice): block c owns h-cols [32c,32c+32).
// hh via f16x3 MFMA (3 gates x 4 K-slice waves), ih from precomputed Gi,
// apply + frag write in-kernel. grid = 32 x 256. One launch per step.
// ---------------------------------------------------------------------------
__global__ __launch_bounds__(256, 2) void k_enc_step(
    const float* __restrict__ Gi_t,
    const f16* __restrict__ WHhi, const f16* __restrict__ WHlo,
    const float* __restrict__ b_hh, float* __restrict__ hT,
    const f16* __restrict__ fin_hi, const f16* __restrict__ fin_lo,
    f16* __restrict__ fout_hi, f16* __restrict__ fout_lo)
{
  __shared__ float cand[4][64][33];
  const int tid = threadIdx.x;
  const int lane = tid & 63;
  const int wv = __builtin_amdgcn_readfirstlane(tid >> 6);
  const int c = blockIdx.x;

  float pr[3][8];
#pragma unroll
  for (int g = 0; g < 3; ++g) {
    f32x16 aM0, aM1, aL0, aL1;
#pragma unroll
    for (int i = 0; i < 16; ++i) { aM0[i] = 0.f; aM1[i] = 0.f; aL0[i] = 0.f; aL1[i] = 0.f; }
    const f16x8* pBh = reinterpret_cast<const f16x8*>(WHhi) + ((long long)(g * 32 + c) * 64 + wv * 16) * 64 + lane;
    const f16x8* pBl = reinterpret_cast<const f16x8*>(WHlo) + ((long long)(g * 32 + c) * 64 + wv * 16) * 64 + lane;
    const f16x8* pAh = reinterpret_cast<const f16x8*>(fin_hi) + (long long)(wv * 16) * 64 + lane;
    const f16x8* pAl = reinterpret_cast<const f16x8*>(fin_lo) + (long long)(wv * 16) * 64 + lane;
#pragma unroll 4
    for (int q = 0; q < 16; ++q) {
      const int o = q * 64;
      f16x8 bh = pBh[o];
      f16x8 bl = pBl[o];
      f16x8 a0 = pAh[o];
      f16x8 a1 = pAh[o + 4096];
      f16x8 l0 = pAl[o];
      f16x8 l1 = pAl[o + 4096];
      aM0 = __builtin_amdgcn_mfma_f32_32x32x16_f16(a0, bh, aM0, 0, 0, 0);
      aM1 = __builtin_amdgcn_mfma_f32_32x32x16_f16(a1, bh, aM1, 0, 0, 0);
      aL0 = __builtin_amdgcn_mfma_f32_32x32x16_f16(a0, bl, aL0, 0, 0, 0);
      aL0 = __builtin_amdgcn_mfma_f32_32x32x16_f16(l0, bh, aL0, 0, 0, 0);
      aL1 = __builtin_amdgcn_mfma_f32_32x32x16_f16(a1, bl, aL1, 0, 0, 0);
      aL1 = __builtin_amdgcn_mfma_f32_32x32x16_f16(l1, bh, aL1, 0, 0, 0);
    }
    __syncthreads();
    {
      const int l = lane & 31;
      const int rbase = 4 * (lane >> 5);
#pragma unroll
      for (int reg = 0; reg < 16; ++reg) {
        const int row = (reg & 3) + 8 * (reg >> 2) + rbase;
        cand[wv][row][l] = aM0[reg] + aL0[reg] * INV2048;
        cand[wv][row + 32][l] = aM1[reg] + aL1[reg] * INV2048;
      }
    }
    __syncthreads();
#pragma unroll
    for (int i = 0; i < 8; ++i) {
      const int idx = i * 256 + tid;
      const int b = idx & 63;
      const int l2 = idx >> 6;
      pr[g][i] = cand[0][b][l2] + cand[1][b][l2] + cand[2][b][l2] + cand[3][b][l2];
    }
  }

#pragma unroll
  for (int i = 0; i < 8; ++i) {
    const int idx = i * 256 + tid;
    const int b = idx & 63;
    const int j = c * 32 + (idx >> 6);
    const float gr = pr[0][i] + Gi_t[(long long)j * 64 + b] + b_hh[j];
    const float gz = pr[1][i] + Gi_t[(long long)(H_ + j) * 64 + b] + b_hh[H_ + j];
    const float gin = Gi_t[(long long)(2 * H_ + j) * 64 + b];
    const float ghn = pr[2][i] + b_hh[2 * H_ + j];
    const float r = 1.f / (1.f + expf(-gr));
    const float z = 1.f / (1.f + expf(-gz));
    const float n = tanhf(fmaf(r, ghn, gin));
    const float hp = hT[(long long)j * 64 + b];
    const float hv = (1.f - z) * n + z * hp;
    hT[(long long)j * 64 + b] = hv;
    write_frag(fout_hi, fout_lo, b, j, hv);
  }
}

// ---------------------------------------------------------------------------
// Decoder step (col-slice): fold 1024-slot partial argmax -> toks, ih via
// on-the-fly E->f16x3 MFMA (3 gates x 4 K-slice waves), hh from preH, apply +
// frag write. grid = 32 x 256. XMODE: 0 = zero input (t=0), 2 = fold.
// ---------------------------------------------------------------------------
template <int XMODE>
__global__ __launch_bounds__(256, 2) void k_dec_step(
    const float* __restrict__ E, const unsigned long long* __restrict__ bp,
    const f16* __restrict__ WIhi, const f16* __restrict__ WIlo,
    const float* __restrict__ b_ih, const float* __restrict__ b_hh,
    const float* __restrict__ preH, float* __restrict__ hT,
    f16* __restrict__ fout_hi, f16* __restrict__ fout_lo)
{
  __shared__ float cand[4][64][33];
  __shared__ int toks[64];
  const int tid = threadIdx.x;
  const int lane = tid & 63;
  const int wv = __builtin_amdgcn_readfirstlane(tid >> 6);
  const int c = blockIdx.x;

  float pr[3][8];
#pragma unroll
  for (int g = 0; g < 3; ++g)
#pragma unroll
    for (int i = 0; i < 8; ++i) pr[g][i] = 0.f;

  if constexpr (XMODE == 2) {
    // fold partial argmax: wave handles 16 rows
    for (int rr = 0; rr < 16; ++rr) {
      const int r = wv * 16 + rr;
      unsigned long long kk = 0ull;
#pragma unroll
      for (int s2 = 0; s2 < 16; ++s2) {
        const unsigned long long q = bp[(long long)r * 1024 + lane + s2 * 64];
        if (q > kk) kk = q;
      }
#pragma unroll
      for (int m = 1; m < 64; m <<= 1) {
        const unsigned long long q = __shfl_xor(kk, m, 64);
        if (q > kk) kk = q;
      }
      if (lane == 0) toks[r] = (int)(0xFFFFFFFFu - (unsigned)(kk & 0xFFFFFFFFull));
    }
    __syncthreads();

    const long long eb0 = (long long)toks[lane & 31] * D_ + (lane >> 5) * 8;
    const long long eb1 = (long long)toks[32 + (lane & 31)] * D_ + (lane >> 5) * 8;

#pragma unroll
    for (int g = 0; g < 3; ++g) {
      f32x16 aM0, aM1, aL0, aL1;
#pragma unroll
      for (int i = 0; i < 16; ++i) { aM0[i] = 0.f; aM1[i] = 0.f; aL0[i] = 0.f; aL1[i] = 0.f; }
      const f16x8* pBh = reinterpret_cast<const f16x8*>(WIhi) + ((long long)(g * 32 + c) * 32 + wv * 8) * 64 + lane;
      const f16x8* pBl = reinterpret_cast<const f16x8*>(WIlo) + ((long long)(g * 32 + c) * 32 + wv * 8) * 64 + lane;
#pragma unroll 2
      for (int q = 0; q < 8; ++q) {
        const int k = (wv * 8 + q) * 16;
        float4 v0 = *reinterpret_cast<const float4*>(E + eb0 + k);
        float4 v1 = *reinterpret_cast<const float4*>(E + eb0 + k + 4);
        float4 u0 = *reinterpret_cast<const float4*>(E + eb1 + k);
        float4 u1 = *reinterpret_cast<const float4*>(E + eb1 + k + 4);
        f16x8 a0, l0, a1, l1;
        cvt8(v0, v1, a0, l0);
        cvt8(u0, u1, a1, l1);
        f16x8 bh = pBh[q * 64];
        f16x8 bl = pBl[q * 64];
        aM0 = __builtin_amdgcn_mfma_f32_32x32x16_f16(a0, bh, aM0, 0, 0, 0);
        aM1 = __builtin_amdgcn_mfma_f32_32x32x16_f16(a1, bh, aM1, 0, 0, 0);
        aL0 = __builtin_amdgcn_mfma_f32_32x32x16_f16(a0, bl, aL0, 0, 0, 0);
        aL0 = __builtin_amdgcn_mfma_f32_32x32x16_f16(l0, bh, aL0, 0, 0, 0);
        aL1 = __builtin_amdgcn_mfma_f32_32x32x16_f16(a1, bl, aL1, 0, 0, 0);
        aL1 = __builtin_amdgcn_mfma_f32_32x32x16_f16(l1, bh, aL1, 0, 0, 0);
      }
      __syncthreads();
      {
        const int l = lane & 31;
        const int rbase = 4 * (lane >> 5);
#pragma unroll
        for (int reg = 0; reg < 16; ++reg) {
          const int row = (reg & 3) + 8 * (reg >> 2) + rbase;
          cand[wv][row][l] = aM0[reg] + aL0[reg] * INV2048;
          cand[wv][row + 32][l] = aM1[reg] + aL1[reg] * INV2048;
        }
      }
      __syncthreads();
#pragma unroll
      for (int i = 0; i < 8; ++i) {
        const int idx = i * 256 + tid;
        const int b = idx & 63;
        const int l2 = idx >> 6;
        pr[g][i] = cand[0][b][l2] + cand[1][b][l2] + cand[2][b][l2] + cand[3][b][l2];
      }
    }
  }

#pragma unroll
  for (int i = 0; i < 8; ++i) {
    const int idx = i * 256 + tid;
    const int b = idx & 63;
    const int j = c * 32 + (idx >> 6);
    const float gr = pr[0][i] + preH[(long long)j * 64 + b] + b_ih[j] + b_hh[j];
    const float gz = pr[1][i] + preH[(long long)(H_ + j) * 64 + b] + b_ih[H_ + j] + b_hh[H_ + j];
    const float gin = pr[2][i] + b_ih[2 * H_ + j];
    const float ghn = preH[(long long)(2 * H_ + j) * 64 + b] + b_hh[2 * H_ + j];
    const float r = 1.f / (1.f + expf(-gr));
    const float z = 1.f / (1.f + expf(-gz));
    const float n = tanhf(fmaf(r, ghn, gin));
    const float hp = hT[(long long)j * 64 + b];
    const float hv = (1.f - z) * n + z * hp;
    hT[(long long)j * 64 + b] = hv;
    write_frag(fout_hi, fout_lo, b, j, hv);
  }
}

// ---------------------------------------------------------------------------
// Fused logits + next-step hh. grid = 1024 x 256 (exactly 4 blocks/CU).
// Blocks [0,1000): logits — ONE n-tile per block, 4-way K-split across waves
// (16 k-iters each), LDS combine, bias, NT store, partial argmax keys.
// Blocks [1000,1024): hh pre-activations for the NEXT GRU step.
// ---------------------------------------------------------------------------
__global__ __launch_bounds__(256, 4) void k_logits_hh(
    const f16* __restrict__ Ahi, const f16* __restrict__ Alo,
    const f16* __restrict__ WOhi, const f16* __restrict__ WOlo,
    const f16* __restrict__ WHhi, const f16* __restrict__ WHlo,
    const float* __restrict__ b_out, float* __restrict__ out,
    unsigned long long* __restrict__ bestPart, float* __restrict__ preH, int t)
{
  __shared__ float cand[4][64][33];
  __shared__ unsigned long long wbest[4][64];
  const int tid = threadIdx.x;
  const int lane = tid & 63;
  const int wv = __builtin_amdgcn_readfirstlane(tid >> 6);

  if (blockIdx.x >= 1000) {
    // ---- hh part for the NEXT step ----
    const int hhb = blockIdx.x - 1000;
    const int nt = hhb * 4 + wv;  // 0..95
    f32x16 aM0, aM1, aL0, aL1;
#pragma unroll
    for (int i = 0; i < 16; ++i) { aM0[i] = 0.f; aM1[i] = 0.f; aL0[i] = 0.f; aL1[i] = 0.f; }
    const f16x8* pB_h = reinterpret_cast<const f16x8*>(WHhi) + ((long long)nt * 64) * 64 + lane;
    const f16x8* pB_l = reinterpret_cast<const f16x8*>(WHlo) + ((long long)nt * 64) * 64 + lane;
    const f16x8* pA_h = reinterpret_cast<const f16x8*>(Ahi) + lane;
    const f16x8* pA_l = reinterpret_cast<const f16x8*>(Alo) + lane;
#pragma unroll 4
    for (int ksi = 0; ksi < 64; ++ksi) {
      const int o = ksi * 64;
      f16x8 bh = pB_h[o];
      f16x8 bl = pB_l[o];
      f16x8 a0 = pA_h[o];
      f16x8 a1 = pA_h[o + 4096];
      f16x8 l0 = pA_l[o];
      f16x8 l1 = pA_l[o + 4096];
      aM0 = __builtin_amdgcn_mfma_f32_32x32x16_f16(a0, bh, aM0, 0, 0, 0);
      aM1 = __builtin_amdgcn_mfma_f32_32x32x16_f16(a1, bh, aM1, 0, 0, 0);
      aL0 = __builtin_amdgcn_mfma_f32_32x32x16_f16(a0, bl, aL0, 0, 0, 0);
      aL0 = __builtin_amdgcn_mfma_f32_32x32x16_f16(l0, bh, aL0, 0, 0, 0);
      aL1 = __builtin_amdgcn_mfma_f32_32x32x16_f16(a1, bl, aL1, 0, 0, 0);
      aL1 = __builtin_amdgcn_mfma_f32_32x32x16_f16(l1, bh, aL1, 0, 0, 0);
    }
    {
      const int l = lane & 31;
      const int rbase = 4 * (lane >> 5);
#pragma unroll
      for (int reg = 0; reg < 16; ++reg) {
        const int row = (reg & 3) + 8 * (reg >> 2) + rbase;
        cand[wv][row][l] = aM0[reg] + aL0[reg] * INV2048;
        cand[wv][row + 32][l] = aM1[reg] + aL1[reg] * INV2048;
      }
    }
    __syncthreads();
#pragma unroll
    for (int i = 0; i < 8; ++i) {
      const int idx = i * 256 + tid;
      const int b4 = (idx & 15) * 4;
      const int nl = idx >> 4;
      float4 o;
      o.x = cand[nl >> 5][b4 + 0][nl & 31];
      o.y = cand[nl >> 5][b4 + 1][nl & 31];
      o.z = cand[nl >> 5][b4 + 2][nl & 31];
      o.w = cand[nl >> 5][b4 + 3][nl & 31];
      *reinterpret_cast<float4*>(&preH[((long long)hhb * 128 + nl) * 64 + b4]) = o;
    }
    return;
  }

  // ---- logits: one n-tile, 4-way K-split ----
  const int nt = blockIdx.x;
  f32x16 accM0, accM1, accL0, accL1;
#pragma unroll
  for (int i = 0; i < 16; ++i) { accM0[i] = 0.f; accM1[i] = 0.f; accL0[i] = 0.f; accL1[i] = 0.f; }

  const int kb = wv * 16 * 64;
  const f16x8* pAh0 = reinterpret_cast<const f16x8*>(Ahi) + kb + lane;
  const f16x8* pAh1 = reinterpret_cast<const f16x8*>(Ahi) + 4096 + kb + lane;
  const f16x8* pAl0 = reinterpret_cast<const f16x8*>(Alo) + kb + lane;
  const f16x8* pAl1 = reinterpret_cast<const f16x8*>(Alo) + 4096 + kb + lane;
  const f16x8* pBh = reinterpret_cast<const f16x8*>(WOhi) + (long long)nt * 4096 + kb + lane;
  const f16x8* pBl = reinterpret_cast<const f16x8*>(WOlo) + (long long)nt * 4096 + kb + lane;

#pragma unroll 4
  for (int ksi = 0; ksi < 16; ++ksi) {
    const int o = ksi * 64;
    f16x8 bh = pBh[o];
    f16x8 bl = pBl[o];
    f16x8 ah0 = pAh0[o];
    f16x8 ah1 = pAh1[o];
    f16x8 al0 = pAl0[o];
    f16x8 al1 = pAl1[o];
    accM0 = __builtin_amdgcn_mfma_f32_32x32x16_f16(ah0, bh, accM0, 0, 0, 0);
    accM1 = __builtin_amdgcn_mfma_f32_32x32x16_f16(ah1, bh, accM1, 0, 0, 0);
    accL0 = __builtin_amdgcn_mfma_f32_32x32x16_f16(ah0, bl, accL0, 0, 0, 0);
    accL0 = __builtin_amdgcn_mfma_f32_32x32x16_f16(al0, bh, accL0, 0, 0, 0);
    accL1 = __builtin_amdgcn_mfma_f32_32x32x16_f16(ah1, bl, accL1, 0, 0, 0);
    accL1 = __builtin_amdgcn_mfma_f32_32x32x16_f16(al1, bh, accL1, 0, 0, 0);
  }

  // partial (K-slice) -> LDS
  {
    const int l31 = lane & 31;
    const int rbase = 4 * (lane >> 5);
#pragma unroll
    for (int reg = 0; reg < 16; ++reg) {
      const int row = (reg & 3) + 8 * (reg >> 2) + rbase;
      cand[wv][row][l31] = accM0[reg] + accL0[reg] * INV2048;
      cand[wv][row + 32][l31] = accM1[reg] + accL1[reg] * INV2048;
    }
  }
  __syncthreads();

  // combine + bias + coalesced NT store + finals in-place (slice 0)
#pragma unroll
  for (int i = 0; i < 8; ++i) {
    const int idx = i * 256 + tid;
    const int col = idx & 31;
    const int row = idx >> 5;  // 0..63
    const int nn = nt * 32 + col;
    const float v = cand[0][row][col] + cand[1][row][col] + cand[2][row][col] +
                    cand[3][row][col] + b_out[nn];
    __builtin_nontemporal_store(v, &out[(long long)row * (T_ * (long long)V_) + (long long)t * V_ + nn]);
    cand[0][row][col] = v;
  }
  __syncthreads();

  // per-row argmax keys: quarter q scans 8 cols of row r
  {
    const int r = tid & 63;
    const int q = tid >> 6;
    unsigned long long kk = 0ull;
#pragma unroll
    for (int cc = 0; cc < 8; ++cc) {
      const int col = q * 8 + cc;
      const float v = cand[0][r][col];
      unsigned u = __float_as_uint(v);
      u = (u & 0x80000000u) ? ~u : (u | 0x80000000u);
      const unsigned long long key = ((unsigned long long)u << 32) |
          (unsigned long long)(0xFFFFFFFFu - (unsigned)(nt * 32 + col));
      if (key > kk) kk = key;
    }
    wbest[q][r] = kk;
  }
  __syncthreads();
  if (tid < 64) {
    unsigned long long kk = wbest[0][tid];
#pragma unroll
    for (int w = 1; w < 4; ++w) { const unsigned long long q = wbest[w][tid]; if (q > kk) kk = q; }
    bestPart[(long long)tid * 1024 + blockIdx.x] = kk;
  }
}

// ---------------------------------------------------------------------------
// mu / logvar / z from hT. grid = 64 x 256.
// ---------------------------------------------------------------------------
__global__ __launch_bounds__(256) void k_mu_lv_z(
    const float* __restrict__ hT, const float* __restrict__ W_mu, const float* __restrict__ b_mu,
    const float* __restrict__ W_lv, const float* __restrict__ b_lv,
    const float* __restrict__ eps, float* __restrict__ out_mu, float* __restrict__ out_lv,
    float* __restrict__ zT)
{
  const int lane = threadIdx.x & 63;
  const int wv = __builtin_amdgcn_readfirstlane(threadIdx.x >> 6);
  const int l = blockIdx.x * 4 + wv;
  const float* wm = W_mu + (long long)l * H_;
  const float* wl = W_lv + (long long)l * H_;
  float am = 0.f, av = 0.f;
#pragma unroll 8
  for (int k = 0; k < H_; ++k) {
    const float h = hT[k * 64 + lane];
    am = fmaf(wm[k], h, am);
    av = fmaf(wl[k], h, av);
  }
  const float mu = am + b_mu[l];
  const float lv = av + b_lv[l];
  out_mu[lane * L_ + l] = mu;
  out_lv[lane * L_ + l] = lv;
  zT[l * 64 + lane] = fmaf(eps[lane * L_ + l], expf(0.5f * lv), mu);
}

// ---------------------------------------------------------------------------
// h_dec0 = z @ W_proj.T + b_proj. grid = 256 x 256.
// ---------------------------------------------------------------------------
__global__ __launch_bounds__(256) void k_proj(
    const float* __restrict__ zT, const float* __restrict__ W_proj,
    const float* __restrict__ b_proj, float* __restrict__ hT0,
    f16* __restrict__ Aohi, f16* __restrict__ Aolo)
{
  const int lane = threadIdx.x & 63;
  const int wv = __builtin_amdgcn_readfirstlane(threadIdx.x >> 6);
  const int j = blockIdx.x * 4 + wv;
  const float* wr = W_proj + (long long)j * L_;
  float acc = 0.f;
#pragma unroll 8
  for (int k = 0; k < L_; ++k) acc = fmaf(wr[k], zT[k * 64 + lane], acc);
  const float hv = acc + b_proj[j];
  hT0[(long long)j * 64 + lane] = hv;
  write_frag(Aohi, Aolo, lane, j, hv);
}

// ---------------------------------------------------------------------------
extern "C" void kernel_launch(void* const* d_in, const int* in_sizes, int n_in,
                              void* d_out, int out_size, void* d_ws, size_t ws_size,
                              hipStream_t stream) {
  (void)in_sizes; (void)n_in; (void)out_size;
  const int*   x        = (const int*)d_in[0];
  const float* eps      = (const float*)d_in[1];
  const float* E        = (const float*)d_in[2];
  const float* W_ih_enc = (const float*)d_in[3];
  const float* W_hh_enc = (const float*)d_in[4];
  const float* b_ih_enc = (const float*)d_in[5];
  const float* b_hh_enc = (const float*)d_in[6];
  const float* W_mu     = (const float*)d_in[7];
  const float* b_mu     = (const float*)d_in[8];
  const float* W_lv     = (const float*)d_in[9];
  const float* b_lv     = (const float*)d_in[10];
  const float* W_proj   = (const float*)d_in[11];
  const float* b_proj   = (const float*)d_in[12];
  const float* W_ih_dec = (const float*)d_in[13];
  const float* W_hh_dec = (const float*)d_in[14];
  const float* b_ih_dec = (const float*)d_in[15];
  const float* b_hh_dec = (const float*)d_in[16];
  const float* W_out    = (const float*)d_in[17];
  const float* b_out    = (const float*)d_in[18];

  float* out = (float*)d_out;
  const long long OFF_MU = (long long)B_ * T_ * V_;
  const long long OFF_LV = OFF_MU + (long long)B_ * L_;

  // Workspace layout (float offsets)
  float* ws = (float*)d_ws;
  float* hA   = ws + 0;                // enc hT (in-place)       65536
  float* dA   = ws + 65536;            // dec hT (in-place)       65536
  float* zT   = ws + 131072;           //                         16384
  unsigned long long* bestPart = (unsigned long long*)(ws + 147456);  // [64][1024] = 131072 fl
  float* preH = ws + 278528;           // [3072][64]              196608
  f16* frAhi  = (f16*)(ws + 475136);   // h A-frags ping          32768 fl
  f16* frAlo  = (f16*)(ws + 507904);
  f16* frBhi  = (f16*)(ws + 540672);   // h A-frags pong
  f16* frBlo  = (f16*)(ws + 573440);
  f16* WHEhi  = (f16*)(ws + 606208);   // [96][64][64][8]         1572864 fl
  f16* WHElo  = (f16*)(ws + 2179072);
  f16* WHDhi  = (f16*)(ws + 3751936);
  f16* WHDlo  = (f16*)(ws + 5324800);
  f16* WIEhi  = (f16*)(ws + 6897664);  // [96][32][64][8]         786432 fl
  f16* WIElo  = (f16*)(ws + 7684096);
  f16* WIDhi  = (f16*)(ws + 8470528);
  f16* WIDlo  = (f16*)(ws + 9256960);
  // overlay: {XAenc + Gi} (encoder) then {WO frags} (decoder)
  f16* XAhi   = (f16*)(ws + 10043392); // [128][32][64][8]        1048576 fl
  f16* XAlo   = (f16*)(ws + 11091968);
  float* Gi   = ws + 12140544;         // [64][3072][64]          12582912
  f16* WOhi   = (f16*)(ws + 10043392); // [1000][64][64][8]       16384000 fl
  f16* WOlo   = (f16*)(ws + 26427392);
  const size_t WS_NEED = (size_t)42811392 * 4;
  if (ws_size < WS_NEED) return;

  hipMemsetAsync(hA, 0, (size_t)H_ * B_ * sizeof(float), stream);
  hipMemsetAsync(frAhi, 0, (size_t)2 * 65536 * sizeof(f16), stream);   // frAhi+frAlo
  hipMemsetAsync(bestPart, 0, (size_t)64 * 1024 * 8, stream);

  // ---- one-time weight packs ----
  k_pack_wf<1024><<<3 * H_, 256, 0, stream>>>(W_hh_enc, WHEhi, WHElo);
  k_pack_wf<1024><<<3 * H_, 256, 0, stream>>>(W_hh_dec, WHDhi, WHDlo);
  k_pack_wf<512><<<3 * H_, 128, 0, stream>>>(W_ih_enc, WIEhi, WIElo);
  k_pack_wf<512><<<3 * H_, 128, 0, stream>>>(W_ih_dec, WIDhi, WIDlo);
  k_pack_xe<<<S_ * B_, 128, 0, stream>>>(x, E, XAhi, XAlo);

  // ---- encoder input gates (one GEMM) ----
  k_gates_mfma<<<64 * 24, 256, 0, stream>>>(XAhi, XAlo, WIEhi, WIElo, b_ih_enc, Gi);

  // ---- encoder: 64 fused steps (1 launch each) ----
  for (int t = 0; t < S_; ++t) {
    const f16* fih = (t & 1) ? frBhi : frAhi;
    const f16* fil = (t & 1) ? frBlo : frAlo;
    f16* foh = (t & 1) ? frAhi : frBhi;
    f16* fol = (t & 1) ? frAlo : frBlo;
    k_enc_step<<<32, 256, 0, stream>>>(Gi + (long long)t * 3 * H_ * B_,
                                       WHEhi, WHElo, b_hh_enc, hA, fih, fil, foh, fol);
  }
  // final h frags in frAhi/frAlo (t=63 odd -> foh = frAhi)

  // ---- latent ----
  k_mu_lv_z<<<64, 256, 0, stream>>>(hA, W_mu, b_mu, W_lv, b_lv, eps,
                                    out + OFF_MU, out + OFF_LV, zT);
  k_proj<<<256, 256, 0, stream>>>(zT, W_proj, b_proj, dA, frAhi, frAlo);

  // ---- pack W_out (overwrites XA+Gi region — both dead now) ----
  k_pack_wf<1024><<<V_, 256, 0, stream>>>(W_out, WOhi, WOlo);

  // ---- initial decoder hh ----
  k_hh_mfma<<<96, 256, 0, stream>>>(frAhi, frAlo, WHDhi, WHDlo, preH);

  // ---- decoder: 64 x (col-slice step + fused logits/hh) ----
  for (int t = 0; t < T_; ++t) {
    if (t == 0) {
      k_dec_step<0><<<32, 256, 0, stream>>>(
          E, nullptr, WIDhi, WIDlo, b_ih_dec, b_hh_dec, preH, dA, frAhi, frAlo);
    } else {
      k_dec_step<2><<<32, 256, 0, stream>>>(
          E, bestPart, WIDhi, WIDlo, b_ih_dec, b_hh_dec, preH, dA, frAhi, frAlo);
    }
    k_logits_hh<<<1024, 256, 0, stream>>>(frAhi, frAlo, WOhi, WOlo, WHDhi, WHDlo,
                                          b_out, out, bestPart, preH, t);
  }
}

// Round 10
// 5754.502 us; speedup vs baseline: 1.3092x; 1.3092x over previous
//
#include <hip/hip_runtime.h>

// Problem constants
#define B_ 64
#define S_ 64
#define T_ 64
#define V_ 32000
#define D_ 512
#define H_ 1024
#define L_ 256

typedef _Float16 f16;
typedef __attribute__((ext_vector_type(4))) _Float16 f16x4;
typedef __attribute__((ext_vector_type(8))) _Float16 f16x8;
typedef __attribute__((ext_vector_type(16))) float f32x16;

#define INV2048 (1.0f / 2048.0f)

// ---------------------------------------------------------------------------
// f16 hi/lo frag write for h values (A-operand layout, m=b, k=j).
// ---------------------------------------------------------------------------
__device__ __forceinline__ void write_frag(f16* __restrict__ Aohi, f16* __restrict__ Aolo,
                                           int b, int j, float hv) {
  const f16 hi = (f16)hv;
  const f16 lo = (f16)((hv - (float)hi) * 2048.0f);
  const long long fo =
      (((long long)(b >> 5) * 64 + (j >> 4)) * 64 + ((b & 31) + 32 * ((j >> 3) & 1))) * 8 + (j & 7);
  Aohi[fo] = hi;
  Aolo[fo] = lo;
}

// ---------------------------------------------------------------------------
// Pack fp32 weights [N][K] into MFMA B-frag-major f16 hi/lo.
// ---------------------------------------------------------------------------
template <int K>
__global__ __launch_bounds__(256) void k_pack_wf(
    const float* __restrict__ W, f16* __restrict__ Bhi, f16* __restrict__ Blo)
{
  const int n = blockIdx.x;
  const int k = threadIdx.x * 4;
  if (k >= K) return;
  float4 w = *reinterpret_cast<const float4*>(W + (long long)n * K + k);
  float wv[4] = {w.x, w.y, w.z, w.w};
  f16x4 hi, lo;
#pragma unroll
  for (int i = 0; i < 4; ++i) {
    const f16 h = (f16)wv[i];
    hi[i] = h;
    lo[i] = (f16)((wv[i] - (float)h) * 2048.0f);
  }
  const int nt = n >> 5;
  const int lane = (n & 31) + 32 * ((k >> 3) & 1);
  const int ks = k >> 4;
  const long long off = (((long long)nt * (K / 16) + ks) * 64 + lane) * 8 + (k & 7);
  *reinterpret_cast<f16x4*>(Bhi + off) = hi;
  *reinterpret_cast<f16x4*>(Blo + off) = lo;
}

// ---------------------------------------------------------------------------
// Pack encoder token embeddings into A-frags (m = s*64+b, K = 512).
// ---------------------------------------------------------------------------
__global__ __launch_bounds__(128) void k_pack_xe(
    const int* __restrict__ x, const float* __restrict__ E,
    f16* __restrict__ XAhi, f16* __restrict__ XAlo)
{
  const int m = blockIdx.x;
  const int s = m >> 6, b = m & 63;
  const int k = threadIdx.x * 4;
  const long long tok = x[b * S_ + s];
  float4 w = *reinterpret_cast<const float4*>(E + tok * D_ + k);
  float wv[4] = {w.x, w.y, w.z, w.w};
  f16x4 hi, lo;
#pragma unroll
  for (int i = 0; i < 4; ++i) {
    const f16 h = (f16)wv[i];
    hi[i] = h;
    lo[i] = (f16)((wv[i] - (float)h) * 2048.0f);
  }
  const int mt = m >> 5;
  const int lane = (m & 31) + 32 * ((k >> 3) & 1);
  const int ks = k >> 4;
  const long long off = (((long long)mt * 32 + ks) * 64 + lane) * 8 + (k & 7);
  *reinterpret_cast<f16x4*>(XAhi + off) = hi;
  *reinterpret_cast<f16x4*>(XAlo + off) = lo;
}

// ---------------------------------------------------------------------------
// Encoder input-gates GEMM (proven kernel).
// ---------------------------------------------------------------------------
__global__ __launch_bounds__(256) void k_gates_mfma(
    const f16* __restrict__ XAhi, const f16* __restrict__ XAlo,
    const f16* __restrict__ Bhi, const f16* __restrict__ Blo,
    const float* __restrict__ b_ih, float* __restrict__ Gi)
{
  __shared__ float cand[4][64][33];
  const int tid = threadIdx.x;
  const int lane = tid & 63;
  const int wv = __builtin_amdgcn_readfirstlane(tid >> 6);
  const int s = blockIdx.x / 24;
  const int ng = blockIdx.x % 24;
  const int nt = ng * 4 + wv;

  f32x16 aM0, aM1, aL0, aL1;
#pragma unroll
  for (int i = 0; i < 16; ++i) { aM0[i] = 0.f; aM1[i] = 0.f; aL0[i] = 0.f; aL1[i] = 0.f; }

  const f16x8* pB_h = reinterpret_cast<const f16x8*>(Bhi) + ((long long)nt * 32) * 64 + lane;
  const f16x8* pB_l = reinterpret_cast<const f16x8*>(Blo) + ((long long)nt * 32) * 64 + lane;
  const f16x8* pA_h = reinterpret_cast<const f16x8*>(XAhi) + ((long long)s * 64) * 64 + lane;
  const f16x8* pA_l = reinterpret_cast<const f16x8*>(XAlo) + ((long long)s * 64) * 64 + lane;

#pragma unroll 4
  for (int ks = 0; ks < 32; ++ks) {
    const int o = ks * 64;
    f16x8 bh = pB_h[o];
    f16x8 bl = pB_l[o];
    f16x8 a0 = pA_h[o];
    f16x8 a1 = pA_h[o + 32 * 64];
    f16x8 l0 = pA_l[o];
    f16x8 l1 = pA_l[o + 32 * 64];
    aM0 = __builtin_amdgcn_mfma_f32_32x32x16_f16(a0, bh, aM0, 0, 0, 0);
    aM1 = __builtin_amdgcn_mfma_f32_32x32x16_f16(a1, bh, aM1, 0, 0, 0);
    aL0 = __builtin_amdgcn_mfma_f32_32x32x16_f16(a0, bl, aL0, 0, 0, 0);
    aL0 = __builtin_amdgcn_mfma_f32_32x32x16_f16(l0, bh, aL0, 0, 0, 0);
    aL1 = __builtin_amdgcn_mfma_f32_32x32x16_f16(a1, bl, aL1, 0, 0, 0);
    aL1 = __builtin_amdgcn_mfma_f32_32x32x16_f16(l1, bh, aL1, 0, 0, 0);
  }

  {
    const int l = lane & 31;
    const int rbase = 4 * (lane >> 5);
#pragma unroll
    for (int reg = 0; reg < 16; ++reg) {
      const int row = (reg & 3) + 8 * (reg >> 2) + rbase;
      cand[wv][row][l] = aM0[reg] + aL0[reg] * INV2048;
      cand[wv][row + 32][l] = aM1[reg] + aL1[reg] * INV2048;
    }
  }
  __syncthreads();
  const int bn0 = ng * 128;
#pragma unroll
  for (int i = 0; i < 8; ++i) {
    const int idx = i * 256 + tid;
    const int b4 = (idx & 15) * 4;
    const int nl = idx >> 4;
    const float bi = b_ih[bn0 + nl];
    float4 o;
    o.x = cand[nl >> 5][b4 + 0][nl & 31] + bi;
    o.y = cand[nl >> 5][b4 + 1][nl & 31] + bi;
    o.z = cand[nl >> 5][b4 + 2][nl & 31] + bi;
    o.w = cand[nl >> 5][b4 + 3][nl & 31] + bi;
    *reinterpret_cast<float4*>(&Gi[((long long)s * (3 * H_) + bn0 + nl) * 64 + b4]) = o;
  }
}

// ---------------------------------------------------------------------------
// hh pre-activations via MFMA: preH[n][b] = h[b,:] . W_hh[n,:]. grid=96x256.
// ---------------------------------------------------------------------------
__global__ __launch_bounds__(256) void k_hh_mfma(
    const f16* __restrict__ Ahi, const f16* __restrict__ Alo,
    const f16* __restrict__ Bhi, const f16* __restrict__ Blo,
    float* __restrict__ preH)
{
  __shared__ float cand[4][64][33];
  const int tid = threadIdx.x;
  const int lane = tid & 63;
  const int wv = __builtin_amdgcn_readfirstlane(tid >> 6);
  const int nt = blockIdx.x;

  f32x16 aM0, aM1, aL0, aL1;
#pragma unroll
  for (int i = 0; i < 16; ++i) { aM0[i] = 0.f; aM1[i] = 0.f; aL0[i] = 0.f; aL1[i] = 0.f; }

  const f16x8* pB_h = reinterpret_cast<const f16x8*>(Bhi) + ((long long)nt * 64 + wv * 16) * 64 + lane;
  const f16x8* pB_l = reinterpret_cast<const f16x8*>(Blo) + ((long long)nt * 64 + wv * 16) * 64 + lane;
  const f16x8* pA_h = reinterpret_cast<const f16x8*>(Ahi) + (long long)(wv * 16) * 64 + lane;
  const f16x8* pA_l = reinterpret_cast<const f16x8*>(Alo) + (long long)(wv * 16) * 64 + lane;

#pragma unroll 4
  for (int q = 0; q < 16; ++q) {
    const int o = q * 64;
    f16x8 bh = pB_h[o];
    f16x8 bl = pB_l[o];
    f16x8 a0 = pA_h[o];
    f16x8 a1 = pA_h[o + 4096];
    f16x8 l0 = pA_l[o];
    f16x8 l1 = pA_l[o + 4096];
    aM0 = __builtin_amdgcn_mfma_f32_32x32x16_f16(a0, bh, aM0, 0, 0, 0);
    aM1 = __builtin_amdgcn_mfma_f32_32x32x16_f16(a1, bh, aM1, 0, 0, 0);
    aL0 = __builtin_amdgcn_mfma_f32_32x32x16_f16(a0, bl, aL0, 0, 0, 0);
    aL0 = __builtin_amdgcn_mfma_f32_32x32x16_f16(l0, bh, aL0, 0, 0, 0);
    aL1 = __builtin_amdgcn_mfma_f32_32x32x16_f16(a1, bl, aL1, 0, 0, 0);
    aL1 = __builtin_amdgcn_mfma_f32_32x32x16_f16(l1, bh, aL1, 0, 0, 0);
  }

  {
    const int l = lane & 31;
    const int rbase = 4 * (lane >> 5);
#pragma unroll
    for (int reg = 0; reg < 16; ++reg) {
      const int row = (reg & 3) + 8 * (reg >> 2) + rbase;
      cand[wv][row][l] = aM0[reg] + aL0[reg] * INV2048;
      cand[wv][row + 32][l] = aM1[reg] + aL1[reg] * INV2048;
    }
  }
  __syncthreads();
#pragma unroll
  for (int i = 0; i < 8; ++i) {
    const int idx = i * 256 + tid;
    const int b = idx & 63;
    const int l = idx >> 6;
    const float v = cand[0][b][l] + cand[1][b][l] + cand[2][b][l] + cand[3][b][l];
    preH[((long long)nt * 32 + l) * 64 + b] = v;
  }
}

// ---------------------------------------------------------------------------
// Encoder apply: gates from preH + Gi_t. grid = 256 x 256.
// ---------------------------------------------------------------------------
__global__ __launch_bounds__(256) void k_apply_enc(
    const float* __restrict__ preH, const float* __restrict__ Gi_t,
    const float* __restrict__ b_hh,
    const float* __restrict__ hT_in, float* __restrict__ hT_out,
    f16* __restrict__ Aohi, f16* __restrict__ Aolo)
{
  const int idx = blockIdx.x * 256 + threadIdx.x;
  const int b = idx & 63;
  const int j = idx >> 6;
  const float gr = preH[(long long)j * 64 + b] + Gi_t[(long long)j * 64 + b] + b_hh[j];
  const float gz = preH[(long long)(H_ + j) * 64 + b] + Gi_t[(long long)(H_ + j) * 64 + b] + b_hh[H_ + j];
  const float gin = Gi_t[(long long)(2 * H_ + j) * 64 + b];
  const float ghn = preH[(long long)(2 * H_ + j) * 64 + b] + b_hh[2 * H_ + j];
  const float r = 1.f / (1.f + expf(-gr));
  const float z = 1.f / (1.f + expf(-gz));
  const float n = tanhf(fmaf(r, ghn, gin));
  const float hp = hT_in[(long long)j * 64 + b];
  const float hv = (1.f - z) * n + z * hp;
  hT_out[(long long)j * 64 + b] = hv;
  write_frag(Aohi, Aolo, b, j, hv);
}

// ---------------------------------------------------------------------------
// Decoder apply: fold 1024-slot partial argmax -> toks, fp32 ih (K=512),
// apply gates with preH. grid = 256 x 1024. XMODE: 0 = zero input, 2 = fold.
// ---------------------------------------------------------------------------
template <int XMODE>
__global__ __launch_bounds__(1024) void k_dec_apply(
    const float* __restrict__ E, const unsigned long long* __restrict__ bp,
    const float* __restrict__ W_ih,
    const float* __restrict__ b_ih, const float* __restrict__ b_hh,
    const float* __restrict__ preH, const float* __restrict__ hT_in,
    float* __restrict__ hT_out, f16* __restrict__ Aohi, f16* __restrict__ Aolo)
{
  __shared__ float4 a_lds[64 * 64];
  __shared__ float red[12 * 3 * 64];
  __shared__ int toks[64];
  const int tid = threadIdx.x;
  const int lane = tid & 63;
  const int wv = __builtin_amdgcn_readfirstlane(tid >> 6);
  const int jj = wv & 3;
  const int ks = wv >> 2;
  const int j = blockIdx.x * 4 + jj;
  const int kf16 = tid & 63;
  const int msub = tid >> 6;

  float accR = 0.f, accZ = 0.f, accIN = 0.f;

  if constexpr (XMODE == 2) {
#pragma unroll
    for (int rr = 0; rr < 4; ++rr) {
      const int r = wv + rr * 16;
      unsigned long long kk = 0ull;
#pragma unroll
      for (int i = 0; i < 16; ++i) {
        const unsigned long long q = bp[(long long)r * 1024 + lane + i * 64];
        if (q > kk) kk = q;
      }
#pragma unroll
      for (int m = 1; m < 64; m <<= 1) {
        const unsigned long long q = __shfl_xor(kk, m, 64);
        if (q > kk) kk = q;
      }
      if (lane == 0) toks[r] = (int)(0xFFFFFFFFu - (unsigned)(kk & 0xFFFFFFFFull));
    }
    __syncthreads();

    const float* wr = W_ih + (long long)j * D_;
    const float* wz = W_ih + (long long)(j + H_) * D_;
    const float* wn = W_ih + (long long)(j + 2 * H_) * D_;
    for (int c = 0; c < 2; ++c) {
      __syncthreads();
#pragma unroll
      for (int p = 0; p < 4; ++p) {
        const int m = p * 16 + msub;
        const long long tok = toks[m];
        float4 v = *reinterpret_cast<const float4*>(E + tok * D_ + c * 256 + kf16 * 4);
        a_lds[m * 64 + (kf16 ^ (m & 7))] = v;
      }
      __syncthreads();
#pragma unroll 4
      for (int q = 0; q < 16; ++q) {
        const int kf = ks * 16 + q;
        float4 a = a_lds[lane * 64 + (kf ^ (lane & 7))];
        float4 w0 = *reinterpret_cast<const float4*>(wr + c * 256 + kf * 4);
        float4 w1 = *reinterpret_cast<const float4*>(wz + c * 256 + kf * 4);
        float4 w2 = *reinterpret_cast<const float4*>(wn + c * 256 + kf * 4);
        accR = fmaf(w0.x, a.x, accR); accR = fmaf(w0.y, a.y, accR);
        accR = fmaf(w0.z, a.z, accR); accR = fmaf(w0.w, a.w, accR);
        accZ = fmaf(w1.x, a.x, accZ); accZ = fmaf(w1.y, a.y, accZ);
        accZ = fmaf(w1.z, a.z, accZ); accZ = fmaf(w1.w, a.w, accZ);
        accIN = fmaf(w2.x, a.x, accIN); accIN = fmaf(w2.y, a.y, accIN);
        accIN = fmaf(w2.z, a.z, accIN); accIN = fmaf(w2.w, a.w, accIN);
      }
    }
  }

  if (ks > 0) {
    float* rp = red + (((ks - 1) * 4 + jj) * 3) * 64 + lane;
    rp[0] = accR; rp[64] = accZ; rp[128] = accIN;
  }
  __syncthreads();
  if (ks == 0) {
#pragma unroll
    for (int t2 = 0; t2 < 3; ++t2) {
      const float* rp = red + ((t2 * 4 + jj) * 3) * 64 + lane;
      accR += rp[0]; accZ += rp[64]; accIN += rp[128];
    }
    const float gr = accR + preH[(long long)j * 64 + lane] + b_ih[j] + b_hh[j];
    const float gz = accZ + preH[(long long)(H_ + j) * 64 + lane] + b_ih[H_ + j] + b_hh[H_ + j];
    const float gin = accIN + b_ih[2 * H_ + j];
    const float ghn = preH[(long long)(2 * H_ + j) * 64 + lane] + b_hh[2 * H_ + j];
    const float r = 1.f / (1.f + expf(-gr));
    const float z = 1.f / (1.f + expf(-gz));
    const float n = tanhf(fmaf(r, ghn, gin));
    const float hp = hT_in[(long long)j * 64 + lane];
    const float hv = (1.f - z) * n + z * hp;
    hT_out[(long long)j * 64 + lane] = hv;
    write_frag(Aohi, Aolo, lane, j, hv);
  }
}

// ---------------------------------------------------------------------------
// Fused logits + next-step hh, WORKLIST form. grid = EXACTLY 256 blocks
// (1/CU, no round quantization). 1096 units: u<1000 = logits n-tile u,
// u>=1000 = hh n-tile (u-1000). Block b handles u = b, b+256, ... Each unit:
// 4-wave K-split (16 k-iters/wave), LDS combine. Max block load 5 units vs
// avg 4.28 (1.17x imbalance, vs 2x in the 274-grid variant).
// ---------------------------------------------------------------------------
__global__ __launch_bounds__(256) void k_logits_hh(
    const f16* __restrict__ Ahi, const f16* __restrict__ Alo,
    const f16* __restrict__ WOhi, const f16* __restrict__ WOlo,
    const f16* __restrict__ WHhi, const f16* __restrict__ WHlo,
    const float* __restrict__ b_out, float* __restrict__ out,
    unsigned long long* __restrict__ bestPart, float* __restrict__ preH, int t)
{
  __shared__ float cand[4][64][33];
  __shared__ unsigned long long wbest[4][64];
  const int tid = threadIdx.x;
  const int lane = tid & 63;
  const int wv = __builtin_amdgcn_readfirstlane(tid >> 6);
  const int kb = wv * 16 * 64;  // K-slice base (f16x8 units)
  const int l31 = lane & 31;
  const int rbase = 4 * (lane >> 5);

  for (int u = blockIdx.x; u < 1096; u += 256) {
    f32x16 aM0, aM1, aL0, aL1;
#pragma unroll
    for (int i = 0; i < 16; ++i) { aM0[i] = 0.f; aM1[i] = 0.f; aL0[i] = 0.f; aL1[i] = 0.f; }

    const bool isLog = (u < 1000);
    const int nt = isLog ? u : (u - 1000);
    const f16x8* pBh = reinterpret_cast<const f16x8*>(isLog ? WOhi : WHhi) + (long long)nt * 4096 + kb + lane;
    const f16x8* pBl = reinterpret_cast<const f16x8*>(isLog ? WOlo : WHlo) + (long long)nt * 4096 + kb + lane;
    const f16x8* pAh = reinterpret_cast<const f16x8*>(Ahi) + kb + lane;
    const f16x8* pAl = reinterpret_cast<const f16x8*>(Alo) + kb + lane;

#pragma unroll 8
    for (int q = 0; q < 16; ++q) {
      const int o = q * 64;
      f16x8 bh = pBh[o];
      f16x8 bl = pBl[o];
      f16x8 a0 = pAh[o];
      f16x8 a1 = pAh[o + 4096];
      f16x8 l0 = pAl[o];
      f16x8 l1 = pAl[o + 4096];
      aM0 = __builtin_amdgcn_mfma_f32_32x32x16_f16(a0, bh, aM0, 0, 0, 0);
      aM1 = __builtin_amdgcn_mfma_f32_32x32x16_f16(a1, bh, aM1, 0, 0, 0);
      aL0 = __builtin_amdgcn_mfma_f32_32x32x16_f16(a0, bl, aL0, 0, 0, 0);
      aL0 = __builtin_amdgcn_mfma_f32_32x32x16_f16(l0, bh, aL0, 0, 0, 0);
      aL1 = __builtin_amdgcn_mfma_f32_32x32x16_f16(a1, bl, aL1, 0, 0, 0);
      aL1 = __builtin_amdgcn_mfma_f32_32x32x16_f16(l1, bh, aL1, 0, 0, 0);
    }

    // K-slice partials -> LDS
#pragma unroll
    for (int reg = 0; reg < 16; ++reg) {
      const int row = (reg & 3) + 8 * (reg >> 2) + rbase;
      cand[wv][row][l31] = aM0[reg] + aL0[reg] * INV2048;
      cand[wv][row + 32][l31] = aM1[reg] + aL1[reg] * INV2048;
    }
    __syncthreads();

    if (isLog) {
      // combine + bias + coalesced NT store; finals kept in slice 0
#pragma unroll
      for (int i = 0; i < 8; ++i) {
        const int idx = i * 256 + tid;
        const int col = idx & 31;
        const int row = idx >> 5;  // batch row 0..63
        const int nn = nt * 32 + col;
        const float v = cand[0][row][col] + cand[1][row][col] + cand[2][row][col] +
                        cand[3][row][col] + b_out[nn];
        __builtin_nontemporal_store(v, &out[(long long)row * (T_ * (long long)V_) + (long long)t * V_ + nn]);
        cand[0][row][col] = v;
      }
      __syncthreads();
      // per-row argmax keys: quarter q scans 8 cols of row r
      {
        const int r = tid & 63;
        const int q = tid >> 6;
        unsigned long long kk = 0ull;
#pragma unroll
        for (int cc = 0; cc < 8; ++cc) {
          const int col = q * 8 + cc;
          const float v = cand[0][r][col];
          unsigned uu = __float_as_uint(v);
          uu = (uu & 0x80000000u) ? ~uu : (uu | 0x80000000u);
          const unsigned long long key = ((unsigned long long)uu << 32) |
              (unsigned long long)(0xFFFFFFFFu - (unsigned)(nt * 32 + col));
          if (key > kk) kk = key;
        }
        wbest[q][r] = kk;
      }
      __syncthreads();
      if (tid < 64) {
        unsigned long long kk = wbest[0][tid];
#pragma unroll
        for (int w = 1; w < 4; ++w) { const unsigned long long q = wbest[w][tid]; if (q > kk) kk = q; }
        bestPart[(long long)tid * 1024 + u] = kk;
      }
      __syncthreads();
    } else {
      // hh combine -> preH (for next GRU step)
#pragma unroll
      for (int i = 0; i < 8; ++i) {
        const int idx = i * 256 + tid;
        const int b = idx & 63;
        const int l = idx >> 6;
        const float v = cand[0][b][l] + cand[1][b][l] + cand[2][b][l] + cand[3][b][l];
        preH[((long long)nt * 32 + l) * 64 + b] = v;
      }
      __syncthreads();
    }
  }
}

// ---------------------------------------------------------------------------
// mu / logvar / z from hT. grid = 64 x 256.
// ---------------------------------------------------------------------------
__global__ __launch_bounds__(256) void k_mu_lv_z(
    const float* __restrict__ hT, const float* __restrict__ W_mu, const float* __restrict__ b_mu,
    const float* __restrict__ W_lv, const float* __restrict__ b_lv,
    const float* __restrict__ eps, float* __restrict__ out_mu, float* __restrict__ out_lv,
    float* __restrict__ zT)
{
  const int lane = threadIdx.x & 63;
  const int wv = __builtin_amdgcn_readfirstlane(threadIdx.x >> 6);
  const int l = blockIdx.x * 4 + wv;
  const float* wm = W_mu + (long long)l * H_;
  const float* wl = W_lv + (long long)l * H_;
  float am = 0.f, av = 0.f;
#pragma unroll 8
  for (int k = 0; k < H_; ++k) {
    const float h = hT[k * 64 + lane];
    am = fmaf(wm[k], h, am);
    av = fmaf(wl[k], h, av);
  }
  const float mu = am + b_mu[l];
  const float lv = av + b_lv[l];
  out_mu[lane * L_ + l] = mu;
  out_lv[lane * L_ + l] = lv;
  zT[l * 64 + lane] = fmaf(eps[lane * L_ + l], expf(0.5f * lv), mu);
}

// ---------------------------------------------------------------------------
// h_dec0 = z @ W_proj.T + b_proj. grid = 256 x 256.
// ---------------------------------------------------------------------------
__global__ __launch_bounds__(256) void k_proj(
    const float* __restrict__ zT, const float* __restrict__ W_proj,
    const float* __restrict__ b_proj, float* __restrict__ hT0,
    f16* __restrict__ Aohi, f16* __restrict__ Aolo)
{
  const int lane = threadIdx.x & 63;
  const int wv = __builtin_amdgcn_readfirstlane(threadIdx.x >> 6);
  const int j = blockIdx.x * 4 + wv;
  const float* wr = W_proj + (long long)j * L_;
  float acc = 0.f;
#pragma unroll 8
  for (int k = 0; k < L_; ++k) acc = fmaf(wr[k], zT[k * 64 + lane], acc);
  const float hv = acc + b_proj[j];
  hT0[(long long)j * 64 + lane] = hv;
  write_frag(Aohi, Aolo, lane, j, hv);
}

// ---------------------------------------------------------------------------
extern "C" void kernel_launch(void* const* d_in, const int* in_sizes, int n_in,
                              void* d_out, int out_size, void* d_ws, size_t ws_size,
                              hipStream_t stream) {
  (void)in_sizes; (void)n_in; (void)out_size;
  const int*   x        = (const int*)d_in[0];
  const float* eps      = (const float*)d_in[1];
  const float* E        = (const float*)d_in[2];
  const float* W_ih_enc = (const float*)d_in[3];
  const float* W_hh_enc = (const float*)d_in[4];
  const float* b_ih_enc = (const float*)d_in[5];
  const float* b_hh_enc = (const float*)d_in[6];
  const float* W_mu     = (const float*)d_in[7];
  const float* b_mu     = (const float*)d_in[8];
  const float* W_lv     = (const float*)d_in[9];
  const float* b_lv     = (const float*)d_in[10];
  const float* W_proj   = (const float*)d_in[11];
  const float* b_proj   = (const float*)d_in[12];
  const float* W_ih_dec = (const float*)d_in[13];
  const float* W_hh_dec = (const float*)d_in[14];
  const float* b_ih_dec = (const float*)d_in[15];
  const float* b_hh_dec = (const float*)d_in[16];
  const float* W_out    = (const float*)d_in[17];
  const float* b_out    = (const float*)d_in[18];

  float* out = (float*)d_out;
  const long long OFF_MU = (long long)B_ * T_ * V_;
  const long long OFF_LV = OFF_MU + (long long)B_ * L_;

  // Workspace layout (float offsets)
  float* ws = (float*)d_ws;
  float* hA   = ws + 0;                // enc hT (in-place)
  float* dA   = ws + 65536;            // dec hT (in-place)
  float* zT   = ws + 131072;           // [256][64]
  unsigned long long* bestPart = (unsigned long long*)(ws + 147456);  // [64][1024] u64
  float* preH = ws + 278528;           // [3072][64]
  f16* frAhi  = (f16*)(ws + 475136);   // h A-frags [2][64][64][8]
  f16* frAlo  = (f16*)(ws + 507904);
  f16* WHEhi  = (f16*)(ws + 540672);   // [96][64][64][8]
  f16* WHElo  = (f16*)(ws + 2113536);
  f16* WHDhi  = (f16*)(ws + 3686400);
  f16* WHDlo  = (f16*)(ws + 5259264);
  f16* WIEhi  = (f16*)(ws + 6832128);  // [96][32][64][8]
  f16* WIElo  = (f16*)(ws + 7618560);
  // overlay: {XAenc + Gi} (encoder) then {WO frags} (decoder)
  f16* XAhi   = (f16*)(ws + 8404992);  // [128][32][64][8]
  f16* XAlo   = (f16*)(ws + 9453568);
  float* Gi   = ws + 10502144;         // [64][3072][64]
  f16* WOhi   = (f16*)(ws + 8404992);  // [1000][64][64][8]
  f16* WOlo   = (f16*)(ws + 24788992);
  const size_t WS_NEED = (size_t)41172992 * 4;
  if (ws_size < WS_NEED) return;

  hipMemsetAsync(hA, 0, (size_t)H_ * B_ * sizeof(float), stream);
  hipMemsetAsync(frAhi, 0, (size_t)2 * 65536 * sizeof(f16), stream);   // frAhi+frAlo
  hipMemsetAsync(bestPart, 0, (size_t)64 * 1024 * 8, stream);

  // ---- one-time weight packs ----
  k_pack_wf<1024><<<3 * H_, 256, 0, stream>>>(W_hh_enc, WHEhi, WHElo);
  k_pack_wf<1024><<<3 * H_, 256, 0, stream>>>(W_hh_dec, WHDhi, WHDlo);
  k_pack_wf<512><<<3 * H_, 128, 0, stream>>>(W_ih_enc, WIEhi, WIElo);
  k_pack_xe<<<S_ * B_, 128, 0, stream>>>(x, E, XAhi, XAlo);

  // ---- encoder input gates (one GEMM) ----
  k_gates_mfma<<<64 * 24, 256, 0, stream>>>(XAhi, XAlo, WIEhi, WIElo, b_ih_enc, Gi);

  // ---- encoder: 64 x (hh MFMA + apply) ----
  for (int t = 0; t < S_; ++t) {
    k_hh_mfma<<<96, 256, 0, stream>>>(frAhi, frAlo, WHEhi, WHElo, preH);
    k_apply_enc<<<256, 256, 0, stream>>>(preH, Gi + (long long)t * 3 * H_ * B_,
                                         b_hh_enc, hA, hA, frAhi, frAlo);
  }

  // ---- latent ----
  k_mu_lv_z<<<64, 256, 0, stream>>>(hA, W_mu, b_mu, W_lv, b_lv, eps,
                                    out + OFF_MU, out + OFF_LV, zT);
  k_proj<<<256, 256, 0, stream>>>(zT, W_proj, b_proj, dA, frAhi, frAlo);

  // ---- pack W_out (overwrites XA+Gi region — both dead now) ----
  k_pack_wf<1024><<<V_, 256, 0, stream>>>(W_out, WOhi, WOlo);

  // ---- initial decoder hh ----
  k_hh_mfma<<<96, 256, 0, stream>>>(frAhi, frAlo, WHDhi, WHDlo, preH);

  // ---- decoder: 64 x (apply + balanced worklist logits/hh) ----
  for (int t = 0; t < T_; ++t) {
    if (t == 0) {
      k_dec_apply<0><<<256, 1024, 0, stream>>>(
          E, nullptr, W_ih_dec, b_ih_dec, b_hh_dec, preH, dA, dA, frAhi, frAlo);
    } else {
      k_dec_apply<2><<<256, 1024, 0, stream>>>(
          E, bestPart, W_ih_dec, b_ih_dec, b_hh_dec, preH, dA, dA, frAhi, frAlo);
    }
    k_logits_hh<<<256, 256, 0, stream>>>(frAhi, frAlo, WOhi, WOlo, WHDhi, WHDlo,
                                         b_out, out, bestPart, preH, t);
  }
}

// Round 11
// 5726.342 us; speedup vs baseline: 1.3156x; 1.0049x over previous
//
#include <hip/hip_runtime.h>

// Problem constants
#define B_ 64
#define S_ 64
#define T_ 64
#define V_ 32000
#define D_ 512
#define H_ 1024
#define L_ 256

typedef _Float16 f16;
typedef __attribute__((ext_vector_type(4))) _Float16 f16x4;
typedef __attribute__((ext_vector_type(8))) _Float16 f16x8;
typedef __attribute__((ext_vector_type(16))) float f32x16;

#define INV2048 (1.0f / 2048.0f)

// ---------------------------------------------------------------------------
// f16 hi/lo frag write for h values (A-operand layout, m=b, k=j).
// ---------------------------------------------------------------------------
__device__ __forceinline__ void write_frag(f16* __restrict__ Aohi, f16* __restrict__ Aolo,
                                           int b, int j, float hv) {
  const f16 hi = (f16)hv;
  const f16 lo = (f16)((hv - (float)hi) * 2048.0f);
  const long long fo =
      (((long long)(b >> 5) * 64 + (j >> 4)) * 64 + ((b & 31) + 32 * ((j >> 3) & 1))) * 8 + (j & 7);
  Aohi[fo] = hi;
  Aolo[fo] = lo;
}

// ---------------------------------------------------------------------------
// Pack fp32 weights [N][K] into MFMA B-frag-major f16 hi/lo.
// ---------------------------------------------------------------------------
template <int K>
__global__ __launch_bounds__(256) void k_pack_wf(
    const float* __restrict__ W, f16* __restrict__ Bhi, f16* __restrict__ Blo)
{
  const int n = blockIdx.x;
  const int k = threadIdx.x * 4;
  if (k >= K) return;
  float4 w = *reinterpret_cast<const float4*>(W + (long long)n * K + k);
  float wv[4] = {w.x, w.y, w.z, w.w};
  f16x4 hi, lo;
#pragma unroll
  for (int i = 0; i < 4; ++i) {
    const f16 h = (f16)wv[i];
    hi[i] = h;
    lo[i] = (f16)((wv[i] - (float)h) * 2048.0f);
  }
  const int nt = n >> 5;
  const int lane = (n & 31) + 32 * ((k >> 3) & 1);
  const int ks = k >> 4;
  const long long off = (((long long)nt * (K / 16) + ks) * 64 + lane) * 8 + (k & 7);
  *reinterpret_cast<f16x4*>(Bhi + off) = hi;
  *reinterpret_cast<f16x4*>(Blo + off) = lo;
}

// ---------------------------------------------------------------------------
// Pack encoder token embeddings into A-frags (m = s*64+b, K = 512).
// ---------------------------------------------------------------------------
__global__ __launch_bounds__(128) void k_pack_xe(
    const int* __restrict__ x, const float* __restrict__ E,
    f16* __restrict__ XAhi, f16* __restrict__ XAlo)
{
  const int m = blockIdx.x;
  const int s = m >> 6, b = m & 63;
  const int k = threadIdx.x * 4;
  const long long tok = x[b * S_ + s];
  float4 w = *reinterpret_cast<const float4*>(E + tok * D_ + k);
  float wv[4] = {w.x, w.y, w.z, w.w};
  f16x4 hi, lo;
#pragma unroll
  for (int i = 0; i < 4; ++i) {
    const f16 h = (f16)wv[i];
    hi[i] = h;
    lo[i] = (f16)((wv[i] - (float)h) * 2048.0f);
  }
  const int mt = m >> 5;
  const int lane = (m & 31) + 32 * ((k >> 3) & 1);
  const int ks = k >> 4;
  const long long off = (((long long)mt * 32 + ks) * 64 + lane) * 8 + (k & 7);
  *reinterpret_cast<f16x4*>(XAhi + off) = hi;
  *reinterpret_cast<f16x4*>(XAlo + off) = lo;
}

// ---------------------------------------------------------------------------
// Encoder input-gates GEMM (proven kernel).
// ---------------------------------------------------------------------------
__global__ __launch_bounds__(256) void k_gates_mfma(
    const f16* __restrict__ XAhi, const f16* __restrict__ XAlo,
    const f16* __restrict__ Bhi, const f16* __restrict__ Blo,
    const float* __restrict__ b_ih, float* __restrict__ Gi)
{
  __shared__ float cand[4][64][33];
  const int tid = threadIdx.x;
  const int lane = tid & 63;
  const int wv = __builtin_amdgcn_readfirstlane(tid >> 6);
  const int s = blockIdx.x / 24;
  const int ng = blockIdx.x % 24;
  const int nt = ng * 4 + wv;

  f32x16 aM0, aM1, aL0, aL1;
#pragma unroll
  for (int i = 0; i < 16; ++i) { aM0[i] = 0.f; aM1[i] = 0.f; aL0[i] = 0.f; aL1[i] = 0.f; }

  const f16x8* pB_h = reinterpret_cast<const f16x8*>(Bhi) + ((long long)nt * 32) * 64 + lane;
  const f16x8* pB_l = reinterpret_cast<const f16x8*>(Blo) + ((long long)nt * 32) * 64 + lane;
  const f16x8* pA_h = reinterpret_cast<const f16x8*>(XAhi) + ((long long)s * 64) * 64 + lane;
  const f16x8* pA_l = reinterpret_cast<const f16x8*>(XAlo) + ((long long)s * 64) * 64 + lane;

#pragma unroll 4
  for (int ks = 0; ks < 32; ++ks) {
    const int o = ks * 64;
    f16x8 bh = pB_h[o];
    f16x8 bl = pB_l[o];
    f16x8 a0 = pA_h[o];
    f16x8 a1 = pA_h[o + 32 * 64];
    f16x8 l0 = pA_l[o];
    f16x8 l1 = pA_l[o + 32 * 64];
    aM0 = __builtin_amdgcn_mfma_f32_32x32x16_f16(a0, bh, aM0, 0, 0, 0);
    aM1 = __builtin_amdgcn_mfma_f32_32x32x16_f16(a1, bh, aM1, 0, 0, 0);
    aL0 = __builtin_amdgcn_mfma_f32_32x32x16_f16(a0, bl, aL0, 0, 0, 0);
    aL0 = __builtin_amdgcn_mfma_f32_32x32x16_f16(l0, bh, aL0, 0, 0, 0);
    aL1 = __builtin_amdgcn_mfma_f32_32x32x16_f16(a1, bl, aL1, 0, 0, 0);
    aL1 = __builtin_amdgcn_mfma_f32_32x32x16_f16(l1, bh, aL1, 0, 0, 0);
  }

  {
    const int l = lane & 31;
    const int rbase = 4 * (lane >> 5);
#pragma unroll
    for (int reg = 0; reg < 16; ++reg) {
      const int row = (reg & 3) + 8 * (reg >> 2) + rbase;
      cand[wv][row][l] = aM0[reg] + aL0[reg] * INV2048;
      cand[wv][row + 32][l] = aM1[reg] + aL1[reg] * INV2048;
    }
  }
  __syncthreads();
  const int bn0 = ng * 128;
#pragma unroll
  for (int i = 0; i < 8; ++i) {
    const int idx = i * 256 + tid;
    const int b4 = (idx & 15) * 4;
    const int nl = idx >> 4;
    const float bi = b_ih[bn0 + nl];
    float4 o;
    o.x = cand[nl >> 5][b4 + 0][nl & 31] + bi;
    o.y = cand[nl >> 5][b4 + 1][nl & 31] + bi;
    o.z = cand[nl >> 5][b4 + 2][nl & 31] + bi;
    o.w = cand[nl >> 5][b4 + 3][nl & 31] + bi;
    *reinterpret_cast<float4*>(&Gi[((long long)s * (3 * H_) + bn0 + nl) * 64 + b4]) = o;
  }
}

// ---------------------------------------------------------------------------
// hh pre-activations via MFMA: preH[n][b] = h[b,:] . W_hh[n,:]. grid=96x256.
// ---------------------------------------------------------------------------
__global__ __launch_bounds__(256) void k_hh_mfma(
    const f16* __restrict__ Ahi, const f16* __restrict__ Alo,
    const f16* __restrict__ Bhi, const f16* __restrict__ Blo,
    float* __restrict__ preH)
{
  __shared__ float cand[4][64][33];
  const int tid = threadIdx.x;
  const int lane = tid & 63;
  const int wv = __builtin_amdgcn_readfirstlane(tid >> 6);
  const int nt = blockIdx.x;

  f32x16 aM0, aM1, aL0, aL1;
#pragma unroll
  for (int i = 0; i < 16; ++i) { aM0[i] = 0.f; aM1[i] = 0.f; aL0[i] = 0.f; aL1[i] = 0.f; }

  const f16x8* pB_h = reinterpret_cast<const f16x8*>(Bhi) + ((long long)nt * 64 + wv * 16) * 64 + lane;
  const f16x8* pB_l = reinterpret_cast<const f16x8*>(Blo) + ((long long)nt * 64 + wv * 16) * 64 + lane;
  const f16x8* pA_h = reinterpret_cast<const f16x8*>(Ahi) + (long long)(wv * 16) * 64 + lane;
  const f16x8* pA_l = reinterpret_cast<const f16x8*>(Alo) + (long long)(wv * 16) * 64 + lane;

#pragma unroll 4
  for (int q = 0; q < 16; ++q) {
    const int o = q * 64;
    f16x8 bh = pB_h[o];
    f16x8 bl = pB_l[o];
    f16x8 a0 = pA_h[o];
    f16x8 a1 = pA_h[o + 4096];
    f16x8 l0 = pA_l[o];
    f16x8 l1 = pA_l[o + 4096];
    aM0 = __builtin_amdgcn_mfma_f32_32x32x16_f16(a0, bh, aM0, 0, 0, 0);
    aM1 = __builtin_amdgcn_mfma_f32_32x32x16_f16(a1, bh, aM1, 0, 0, 0);
    aL0 = __builtin_amdgcn_mfma_f32_32x32x16_f16(a0, bl, aL0, 0, 0, 0);
    aL0 = __builtin_amdgcn_mfma_f32_32x32x16_f16(l0, bh, aL0, 0, 0, 0);
    aL1 = __builtin_amdgcn_mfma_f32_32x32x16_f16(a1, bl, aL1, 0, 0, 0);
    aL1 = __builtin_amdgcn_mfma_f32_32x32x16_f16(l1, bh, aL1, 0, 0, 0);
  }

  {
    const int l = lane & 31;
    const int rbase = 4 * (lane >> 5);
#pragma unroll
    for (int reg = 0; reg < 16; ++reg) {
      const int row = (reg & 3) + 8 * (reg >> 2) + rbase;
      cand[wv][row][l] = aM0[reg] + aL0[reg] * INV2048;
      cand[wv][row + 32][l] = aM1[reg] + aL1[reg] * INV2048;
    }
  }
  __syncthreads();
#pragma unroll
  for (int i = 0; i < 8; ++i) {
    const int idx = i * 256 + tid;
    const int b = idx & 63;
    const int l = idx >> 6;
    const float v = cand[0][b][l] + cand[1][b][l] + cand[2][b][l] + cand[3][b][l];
    preH[((long long)nt * 32 + l) * 64 + b] = v;
  }
}

// ---------------------------------------------------------------------------
// Encoder apply: gates from preH + Gi_t. grid = 256 x 256.
// ---------------------------------------------------------------------------
__global__ __launch_bounds__(256) void k_apply_enc(
    const float* __restrict__ preH, const float* __restrict__ Gi_t,
    const float* __restrict__ b_hh,
    const float* __restrict__ hT_in, float* __restrict__ hT_out,
    f16* __restrict__ Aohi, f16* __restrict__ Aolo)
{
  const int idx = blockIdx.x * 256 + threadIdx.x;
  const int b = idx & 63;
  const int j = idx >> 6;
  const float gr = preH[(long long)j * 64 + b] + Gi_t[(long long)j * 64 + b] + b_hh[j];
  const float gz = preH[(long long)(H_ + j) * 64 + b] + Gi_t[(long long)(H_ + j) * 64 + b] + b_hh[H_ + j];
  const float gin = Gi_t[(long long)(2 * H_ + j) * 64 + b];
  const float ghn = preH[(long long)(2 * H_ + j) * 64 + b] + b_hh[2 * H_ + j];
  const float r = 1.f / (1.f + expf(-gr));
  const float z = 1.f / (1.f + expf(-gz));
  const float n = tanhf(fmaf(r, ghn, gin));
  const float hp = hT_in[(long long)j * 64 + b];
  const float hv = (1.f - z) * n + z * hp;
  hT_out[(long long)j * 64 + b] = hv;
  write_frag(Aohi, Aolo, b, j, hv);
}

// ---------------------------------------------------------------------------
// Decoder apply: fold 1024-slot partial argmax -> toks, fp32 ih (K=512),
// apply gates with preH. grid = 256 x 1024. XMODE: 0 = zero input, 2 = fold.
// ---------------------------------------------------------------------------
template <int XMODE>
__global__ __launch_bounds__(1024) void k_dec_apply(
    const float* __restrict__ E, const unsigned long long* __restrict__ bp,
    const float* __restrict__ W_ih,
    const float* __restrict__ b_ih, const float* __restrict__ b_hh,
    const float* __restrict__ preH, const float* __restrict__ hT_in,
    float* __restrict__ hT_out, f16* __restrict__ Aohi, f16* __restrict__ Aolo)
{
  __shared__ float4 a_lds[64 * 64];
  __shared__ float red[12 * 3 * 64];
  __shared__ int toks[64];
  const int tid = threadIdx.x;
  const int lane = tid & 63;
  const int wv = __builtin_amdgcn_readfirstlane(tid >> 6);
  const int jj = wv & 3;
  const int ks = wv >> 2;
  const int j = blockIdx.x * 4 + jj;
  const int kf16 = tid & 63;
  const int msub = tid >> 6;

  float accR = 0.f, accZ = 0.f, accIN = 0.f;

  if constexpr (XMODE == 2) {
#pragma unroll
    for (int rr = 0; rr < 4; ++rr) {
      const int r = wv + rr * 16;
      unsigned long long kk = 0ull;
#pragma unroll
      for (int i = 0; i < 16; ++i) {
        const unsigned long long q = bp[(long long)r * 1024 + lane + i * 64];
        if (q > kk) kk = q;
      }
#pragma unroll
      for (int m = 1; m < 64; m <<= 1) {
        const unsigned long long q = __shfl_xor(kk, m, 64);
        if (q > kk) kk = q;
      }
      if (lane == 0) toks[r] = (int)(0xFFFFFFFFu - (unsigned)(kk & 0xFFFFFFFFull));
    }
    __syncthreads();

    const float* wr = W_ih + (long long)j * D_;
    const float* wz = W_ih + (long long)(j + H_) * D_;
    const float* wn = W_ih + (long long)(j + 2 * H_) * D_;
    for (int c = 0; c < 2; ++c) {
      __syncthreads();
#pragma unroll
      for (int p = 0; p < 4; ++p) {
        const int m = p * 16 + msub;
        const long long tok = toks[m];
        float4 v = *reinterpret_cast<const float4*>(E + tok * D_ + c * 256 + kf16 * 4);
        a_lds[m * 64 + (kf16 ^ (m & 7))] = v;
      }
      __syncthreads();
#pragma unroll 4
      for (int q = 0; q < 16; ++q) {
        const int kf = ks * 16 + q;
        float4 a = a_lds[lane * 64 + (kf ^ (lane & 7))];
        float4 w0 = *reinterpret_cast<const float4*>(wr + c * 256 + kf * 4);
        float4 w1 = *reinterpret_cast<const float4*>(wz + c * 256 + kf * 4);
        float4 w2 = *reinterpret_cast<const float4*>(wn + c * 256 + kf * 4);
        accR = fmaf(w0.x, a.x, accR); accR = fmaf(w0.y, a.y, accR);
        accR = fmaf(w0.z, a.z, accR); accR = fmaf(w0.w, a.w, accR);
        accZ = fmaf(w1.x, a.x, accZ); accZ = fmaf(w1.y, a.y, accZ);
        accZ = fmaf(w1.z, a.z, accZ); accZ = fmaf(w1.w, a.w, accZ);
        accIN = fmaf(w2.x, a.x, accIN); accIN = fmaf(w2.y, a.y, accIN);
        accIN = fmaf(w2.z, a.z, accIN); accIN = fmaf(w2.w, a.w, accIN);
      }
    }
  }

  if (ks > 0) {
    float* rp = red + (((ks - 1) * 4 + jj) * 3) * 64 + lane;
    rp[0] = accR; rp[64] = accZ; rp[128] = accIN;
  }
  __syncthreads();
  if (ks == 0) {
#pragma unroll
    for (int t2 = 0; t2 < 3; ++t2) {
      const float* rp = red + ((t2 * 4 + jj) * 3) * 64 + lane;
      accR += rp[0]; accZ += rp[64]; accIN += rp[128];
    }
    const float gr = accR + preH[(long long)j * 64 + lane] + b_ih[j] + b_hh[j];
    const float gz = accZ + preH[(long long)(H_ + j) * 64 + lane] + b_ih[H_ + j] + b_hh[H_ + j];
    const float gin = accIN + b_ih[2 * H_ + j];
    const float ghn = preH[(long long)(2 * H_ + j) * 64 + lane] + b_hh[2 * H_ + j];
    const float r = 1.f / (1.f + expf(-gr));
    const float z = 1.f / (1.f + expf(-gz));
    const float n = tanhf(fmaf(r, ghn, gin));
    const float hp = hT_in[(long long)j * 64 + lane];
    const float hv = (1.f - z) * n + z * hp;
    hT_out[(long long)j * 64 + lane] = hv;
    write_frag(Aohi, Aolo, lane, j, hv);
  }
}

// ---------------------------------------------------------------------------
// Fused logits + next-step hh, WORKLIST form at 2 blocks/CU. grid = 512.
// 1096 units: u<1000 = logits n-tile u, u>=1000 = hh n-tile (u-1000).
// Block b handles u = b, b+512 [, b+1024]. Each unit: 4-wave K-split
// (16 k-iters/wave), LDS combine. 2 resident blocks/CU (LDS 36KB x2 < 160KB)
// give 2 waves/SIMD so one block's memory stalls hide under the other's MFMAs.
// ---------------------------------------------------------------------------
__global__ __launch_bounds__(256) void k_logits_hh(
    const f16* __restrict__ Ahi, const f16* __restrict__ Alo,
    const f16* __restrict__ WOhi, const f16* __restrict__ WOlo,
    const f16* __restrict__ WHhi, const f16* __restrict__ WHlo,
    const float* __restrict__ b_out, float* __restrict__ out,
    unsigned long long* __restrict__ bestPart, float* __restrict__ preH, int t)
{
  __shared__ float cand[4][64][33];
  __shared__ unsigned long long wbest[4][64];
  const int tid = threadIdx.x;
  const int lane = tid & 63;
  const int wv = __builtin_amdgcn_readfirstlane(tid >> 6);
  const int kb = wv * 16 * 64;  // K-slice base (f16x8 units)
  const int l31 = lane & 31;
  const int rbase = 4 * (lane >> 5);

  for (int u = blockIdx.x; u < 1096; u += 512) {
    f32x16 aM0, aM1, aL0, aL1;
#pragma unroll
    for (int i = 0; i < 16; ++i) { aM0[i] = 0.f; aM1[i] = 0.f; aL0[i] = 0.f; aL1[i] = 0.f; }

    const bool isLog = (u < 1000);
    const int nt = isLog ? u : (u - 1000);
    const f16x8* pBh = reinterpret_cast<const f16x8*>(isLog ? WOhi : WHhi) + (long long)nt * 4096 + kb + lane;
    const f16x8* pBl = reinterpret_cast<const f16x8*>(isLog ? WOlo : WHlo) + (long long)nt * 4096 + kb + lane;
    const f16x8* pAh = reinterpret_cast<const f16x8*>(Ahi) + kb + lane;
    const f16x8* pAl = reinterpret_cast<const f16x8*>(Alo) + kb + lane;

    __builtin_amdgcn_s_setprio(1);
#pragma unroll 8
    for (int q = 0; q < 16; ++q) {
      const int o = q * 64;
      f16x8 bh = pBh[o];
      f16x8 bl = pBl[o];
      f16x8 a0 = pAh[o];
      f16x8 a1 = pAh[o + 4096];
      f16x8 l0 = pAl[o];
      f16x8 l1 = pAl[o + 4096];
      aM0 = __builtin_amdgcn_mfma_f32_32x32x16_f16(a0, bh, aM0, 0, 0, 0);
      aM1 = __builtin_amdgcn_mfma_f32_32x32x16_f16(a1, bh, aM1, 0, 0, 0);
      aL0 = __builtin_amdgcn_mfma_f32_32x32x16_f16(a0, bl, aL0, 0, 0, 0);
      aL0 = __builtin_amdgcn_mfma_f32_32x32x16_f16(l0, bh, aL0, 0, 0, 0);
      aL1 = __builtin_amdgcn_mfma_f32_32x32x16_f16(a1, bl, aL1, 0, 0, 0);
      aL1 = __builtin_amdgcn_mfma_f32_32x32x16_f16(l1, bh, aL1, 0, 0, 0);
    }
    __builtin_amdgcn_s_setprio(0);

    // K-slice partials -> LDS
#pragma unroll
    for (int reg = 0; reg < 16; ++reg) {
      const int row = (reg & 3) + 8 * (reg >> 2) + rbase;
      cand[wv][row][l31] = aM0[reg] + aL0[reg] * INV2048;
      cand[wv][row + 32][l31] = aM1[reg] + aL1[reg] * INV2048;
    }
    __syncthreads();

    if (isLog) {
      // combine + bias + coalesced NT store; finals kept in slice 0
#pragma unroll
      for (int i = 0; i < 8; ++i) {
        const int idx = i * 256 + tid;
        const int col = idx & 31;
        const int row = idx >> 5;  // batch row 0..63
        const int nn = nt * 32 + col;
        const float v = cand[0][row][col] + cand[1][row][col] + cand[2][row][col] +
                        cand[3][row][col] + b_out[nn];
        __builtin_nontemporal_store(v, &out[(long long)row * (T_ * (long long)V_) + (long long)t * V_ + nn]);
        cand[0][row][col] = v;
      }
      __syncthreads();
      // per-row argmax keys: quarter q scans 8 cols of row r
      {
        const int r = tid & 63;
        const int q = tid >> 6;
        unsigned long long kk = 0ull;
#pragma unroll
        for (int cc = 0; cc < 8; ++cc) {
          const int col = q * 8 + cc;
          const float v = cand[0][r][col];
          unsigned uu = __float_as_uint(v);
          uu = (uu & 0x80000000u) ? ~uu : (uu | 0x80000000u);
          const unsigned long long key = ((unsigned long long)uu << 32) |
              (unsigned long long)(0xFFFFFFFFu - (unsigned)(nt * 32 + col));
          if (key > kk) kk = key;
        }
        wbest[q][r] = kk;
      }
      __syncthreads();
      if (tid < 64) {
        unsigned long long kk = wbest[0][tid];
#pragma unroll
        for (int w = 1; w < 4; ++w) { const unsigned long long q = wbest[w][tid]; if (q > kk) kk = q; }
        bestPart[(long long)tid * 1024 + u] = kk;
      }
      __syncthreads();
    } else {
      // hh combine -> preH (for next GRU step)
#pragma unroll
      for (int i = 0; i < 8; ++i) {
        const int idx = i * 256 + tid;
        const int b = idx & 63;
        const int l = idx >> 6;
        const float v = cand[0][b][l] + cand[1][b][l] + cand[2][b][l] + cand[3][b][l];
        preH[((long long)nt * 32 + l) * 64 + b] = v;
      }
      __syncthreads();
    }
  }
}

// ---------------------------------------------------------------------------
// mu / logvar / z from hT. grid = 64 x 256.
// ---------------------------------------------------------------------------
__global__ __launch_bounds__(256) void k_mu_lv_z(
    const float* __restrict__ hT, const float* __restrict__ W_mu, const float* __restrict__ b_mu,
    const float* __restrict__ W_lv, const float* __restrict__ b_lv,
    const float* __restrict__ eps, float* __restrict__ out_mu, float* __restrict__ out_lv,
    float* __restrict__ zT)
{
  const int lane = threadIdx.x & 63;
  const int wv = __builtin_amdgcn_readfirstlane(threadIdx.x >> 6);
  const int l = blockIdx.x * 4 + wv;
  const float* wm = W_mu + (long long)l * H_;
  const float* wl = W_lv + (long long)l * H_;
  float am = 0.f, av = 0.f;
#pragma unroll 8
  for (int k = 0; k < H_; ++k) {
    const float h = hT[k * 64 + lane];
    am = fmaf(wm[k], h, am);
    av = fmaf(wl[k], h, av);
  }
  const float mu = am + b_mu[l];
  const float lv = av + b_lv[l];
  out_mu[lane * L_ + l] = mu;
  out_lv[lane * L_ + l] = lv;
  zT[l * 64 + lane] = fmaf(eps[lane * L_ + l], expf(0.5f * lv), mu);
}

// ---------------------------------------------------------------------------
// h_dec0 = z @ W_proj.T + b_proj. grid = 256 x 256.
// ---------------------------------------------------------------------------
__global__ __launch_bounds__(256) void k_proj(
    const float* __restrict__ zT, const float* __restrict__ W_proj,
    const float* __restrict__ b_proj, float* __restrict__ hT0,
    f16* __restrict__ Aohi, f16* __restrict__ Aolo)
{
  const int lane = threadIdx.x & 63;
  const int wv = __builtin_amdgcn_readfirstlane(threadIdx.x >> 6);
  const int j = blockIdx.x * 4 + wv;
  const float* wr = W_proj + (long long)j * L_;
  float acc = 0.f;
#pragma unroll 8
  for (int k = 0; k < L_; ++k) acc = fmaf(wr[k], zT[k * 64 + lane], acc);
  const float hv = acc + b_proj[j];
  hT0[(long long)j * 64 + lane] = hv;
  write_frag(Aohi, Aolo, lane, j, hv);
}

// ---------------------------------------------------------------------------
extern "C" void kernel_launch(void* const* d_in, const int* in_sizes, int n_in,
                              void* d_out, int out_size, void* d_ws, size_t ws_size,
                              hipStream_t stream) {
  (void)in_sizes; (void)n_in; (void)out_size;
  const int*   x        = (const int*)d_in[0];
  const float* eps      = (const float*)d_in[1];
  const float* E        = (const float*)d_in[2];
  const float* W_ih_enc = (const float*)d_in[3];
  const float* W_hh_enc = (const float*)d_in[4];
  const float* b_ih_enc = (const float*)d_in[5];
  const float* b_hh_enc = (const float*)d_in[6];
  const float* W_mu     = (const float*)d_in[7];
  const float* b_mu     = (const float*)d_in[8];
  const float* W_lv     = (const float*)d_in[9];
  const float* b_lv     = (const float*)d_in[10];
  const float* W_proj   = (const float*)d_in[11];
  const float* b_proj   = (const float*)d_in[12];
  const float* W_ih_dec = (const float*)d_in[13];
  const float* W_hh_dec = (const float*)d_in[14];
  const float* b_ih_dec = (const float*)d_in[15];
  const float* b_hh_dec = (const float*)d_in[16];
  const float* W_out    = (const float*)d_in[17];
  const float* b_out    = (const float*)d_in[18];

  float* out = (float*)d_out;
  const long long OFF_MU = (long long)B_ * T_ * V_;
  const long long OFF_LV = OFF_MU + (long long)B_ * L_;

  // Workspace layout (float offsets)
  float* ws = (float*)d_ws;
  float* hA   = ws + 0;                // enc hT (in-place)
  float* dA   = ws + 65536;            // dec hT (in-place)
  float* zT   = ws + 131072;           // [256][64]
  unsigned long long* bestPart = (unsigned long long*)(ws + 147456);  // [64][1024] u64
  float* preH = ws + 278528;           // [3072][64]
  f16* frAhi  = (f16*)(ws + 475136);   // h A-frags [2][64][64][8]
  f16* frAlo  = (f16*)(ws + 507904);
  f16* WHEhi  = (f16*)(ws + 540672);   // [96][64][64][8]
  f16* WHElo  = (f16*)(ws + 2113536);
  f16* WHDhi  = (f16*)(ws + 3686400);
  f16* WHDlo  = (f16*)(ws + 5259264);
  f16* WIEhi  = (f16*)(ws + 6832128);  // [96][32][64][8]
  f16* WIElo  = (f16*)(ws + 7618560);
  // overlay: {XAenc + Gi} (encoder) then {WO frags} (decoder)
  f16* XAhi   = (f16*)(ws + 8404992);  // [128][32][64][8]
  f16* XAlo   = (f16*)(ws + 9453568);
  float* Gi   = ws + 10502144;         // [64][3072][64]
  f16* WOhi   = (f16*)(ws + 8404992);  // [1000][64][64][8]
  f16* WOlo   = (f16*)(ws + 24788992);
  const size_t WS_NEED = (size_t)41172992 * 4;
  if (ws_size < WS_NEED) return;

  hipMemsetAsync(hA, 0, (size_t)H_ * B_ * sizeof(float), stream);
  hipMemsetAsync(frAhi, 0, (size_t)2 * 65536 * sizeof(f16), stream);   // frAhi+frAlo
  hipMemsetAsync(bestPart, 0, (size_t)64 * 1024 * 8, stream);

  // ---- one-time weight packs ----
  k_pack_wf<1024><<<3 * H_, 256, 0, stream>>>(W_hh_enc, WHEhi, WHElo);
  k_pack_wf<1024><<<3 * H_, 256, 0, stream>>>(W_hh_dec, WHDhi, WHDlo);
  k_pack_wf<512><<<3 * H_, 128, 0, stream>>>(W_ih_enc, WIEhi, WIElo);
  k_pack_xe<<<S_ * B_, 128, 0, stream>>>(x, E, XAhi, XAlo);

  // ---- encoder input gates (one GEMM) ----
  k_gates_mfma<<<64 * 24, 256, 0, stream>>>(XAhi, XAlo, WIEhi, WIElo, b_ih_enc, Gi);

  // ---- encoder: 64 x (hh MFMA + apply) ----
  for (int t = 0; t < S_; ++t) {
    k_hh_mfma<<<96, 256, 0, stream>>>(frAhi, frAlo, WHEhi, WHElo, preH);
    k_apply_enc<<<256, 256, 0, stream>>>(preH, Gi + (long long)t * 3 * H_ * B_,
                                         b_hh_enc, hA, hA, frAhi, frAlo);
  }

  // ---- latent ----
  k_mu_lv_z<<<64, 256, 0, stream>>>(hA, W_mu, b_mu, W_lv, b_lv, eps,
                                    out + OFF_MU, out + OFF_LV, zT);
  k_proj<<<256, 256, 0, stream>>>(zT, W_proj, b_proj, dA, frAhi, frAlo);

  // ---- pack W_out (overwrites XA+Gi region — both dead now) ----
  k_pack_wf<1024><<<V_, 256, 0, stream>>>(W_out, WOhi, WOlo);

  // ---- initial decoder hh ----
  k_hh_mfma<<<96, 256, 0, stream>>>(frAhi, frAlo, WHDhi, WHDlo, preH);

  // ---- decoder: 64 x (apply + balanced worklist logits/hh @ 2 blocks/CU) ----
  for (int t = 0; t < T_; ++t) {
    if (t == 0) {
      k_dec_apply<0><<<256, 1024, 0, stream>>>(
          E, nullptr, W_ih_dec, b_ih_dec, b_hh_dec, preH, dA, dA, frAhi, frAlo);
    } else {
      k_dec_apply<2><<<256, 1024, 0, stream>>>(
          E, bestPart, W_ih_dec, b_ih_dec, b_hh_dec, preH, dA, dA, frAhi, frAlo);
    }
    k_logits_hh<<<512, 256, 0, stream>>>(frAhi, frAlo, WOhi, WOlo, WHDhi, WHDlo,
                                         b_out, out, bestPart, preH, t);
  }
}

// Round 12
// 5341.519 us; speedup vs baseline: 1.4104x; 1.0720x over previous
//
#include <hip/hip_runtime.h>

// Problem constants
#define B_ 64
#define S_ 64
#define T_ 64
#define V_ 32000
#define D_ 512
#define H_ 1024
#define L_ 256

typedef _Float16 f16;
typedef __attribute__((ext_vector_type(4))) _Float16 f16x4;
typedef __attribute__((ext_vector_type(8))) _Float16 f16x8;
typedef __attribute__((ext_vector_type(16))) float f32x16;

#define INV2048 (1.0f / 2048.0f)

// ---------------------------------------------------------------------------
// f16 hi/lo frag write for h values (A-operand layout, m=b, k=j).
// ---------------------------------------------------------------------------
__device__ __forceinline__ void write_frag(f16* __restrict__ Aohi, f16* __restrict__ Aolo,
                                           int b, int j, float hv) {
  const f16 hi = (f16)hv;
  const f16 lo = (f16)((hv - (float)hi) * 2048.0f);
  const long long fo =
      (((long long)(b >> 5) * 64 + (j >> 4)) * 64 + ((b & 31) + 32 * ((j >> 3) & 1))) * 8 + (j & 7);
  Aohi[fo] = hi;
  Aolo[fo] = lo;
}

// ---------------------------------------------------------------------------
// Pack fp32 weights [N][K] into MFMA B-frag-major f16 hi/lo.
// ---------------------------------------------------------------------------
template <int K>
__global__ __launch_bounds__(256) void k_pack_wf(
    const float* __restrict__ W, f16* __restrict__ Bhi, f16* __restrict__ Blo)
{
  const int n = blockIdx.x;
  const int k = threadIdx.x * 4;
  if (k >= K) return;
  float4 w = *reinterpret_cast<const float4*>(W + (long long)n * K + k);
  float wv[4] = {w.x, w.y, w.z, w.w};
  f16x4 hi, lo;
#pragma unroll
  for (int i = 0; i < 4; ++i) {
    const f16 h = (f16)wv[i];
    hi[i] = h;
    lo[i] = (f16)((wv[i] - (float)h) * 2048.0f);
  }
  const int nt = n >> 5;
  const int lane = (n & 31) + 32 * ((k >> 3) & 1);
  const int ks = k >> 4;
  const long long off = (((long long)nt * (K / 16) + ks) * 64 + lane) * 8 + (k & 7);
  *reinterpret_cast<f16x4*>(Bhi + off) = hi;
  *reinterpret_cast<f16x4*>(Blo + off) = lo;
}

// ---------------------------------------------------------------------------
// Pack encoder token embeddings into A-frags (m = s*64+b, K = 512).
// ---------------------------------------------------------------------------
__global__ __launch_bounds__(128) void k_pack_xe(
    const int* __restrict__ x, const float* __restrict__ E,
    f16* __restrict__ XAhi, f16* __restrict__ XAlo)
{
  const int m = blockIdx.x;
  const int s = m >> 6, b = m & 63;
  const int k = threadIdx.x * 4;
  const long long tok = x[b * S_ + s];
  float4 w = *reinterpret_cast<const float4*>(E + tok * D_ + k);
  float wv[4] = {w.x, w.y, w.z, w.w};
  f16x4 hi, lo;
#pragma unroll
  for (int i = 0; i < 4; ++i) {
    const f16 h = (f16)wv[i];
    hi[i] = h;
    lo[i] = (f16)((wv[i] - (float)h) * 2048.0f);
  }
  const int mt = m >> 5;
  const int lane = (m & 31) + 32 * ((k >> 3) & 1);
  const int ks = k >> 4;
  const long long off = (((long long)mt * 32 + ks) * 64 + lane) * 8 + (k & 7);
  *reinterpret_cast<f16x4*>(XAhi + off) = hi;
  *reinterpret_cast<f16x4*>(XAlo + off) = lo;
}

// ---------------------------------------------------------------------------
// Encoder input-gates GEMM (proven kernel).
// ---------------------------------------------------------------------------
__global__ __launch_bounds__(256) void k_gates_mfma(
    const f16* __restrict__ XAhi, const f16* __restrict__ XAlo,
    const f16* __restrict__ Bhi, const f16* __restrict__ Blo,
    const float* __restrict__ b_ih, float* __restrict__ Gi)
{
  __shared__ float cand[4][64][33];
  const int tid = threadIdx.x;
  const int lane = tid & 63;
  const int wv = __builtin_amdgcn_readfirstlane(tid >> 6);
  const int s = blockIdx.x / 24;
  const int ng = blockIdx.x % 24;
  const int nt = ng * 4 + wv;

  f32x16 aM0, aM1, aL0, aL1;
#pragma unroll
  for (int i = 0; i < 16; ++i) { aM0[i] = 0.f; aM1[i] = 0.f; aL0[i] = 0.f; aL1[i] = 0.f; }

  const f16x8* pB_h = reinterpret_cast<const f16x8*>(Bhi) + ((long long)nt * 32) * 64 + lane;
  const f16x8* pB_l = reinterpret_cast<const f16x8*>(Blo) + ((long long)nt * 32) * 64 + lane;
  const f16x8* pA_h = reinterpret_cast<const f16x8*>(XAhi) + ((long long)s * 64) * 64 + lane;
  const f16x8* pA_l = reinterpret_cast<const f16x8*>(XAlo) + ((long long)s * 64) * 64 + lane;

#pragma unroll 4
  for (int ks = 0; ks < 32; ++ks) {
    const int o = ks * 64;
    f16x8 bh = pB_h[o];
    f16x8 bl = pB_l[o];
    f16x8 a0 = pA_h[o];
    f16x8 a1 = pA_h[o + 32 * 64];
    f16x8 l0 = pA_l[o];
    f16x8 l1 = pA_l[o + 32 * 64];
    aM0 = __builtin_amdgcn_mfma_f32_32x32x16_f16(a0, bh, aM0, 0, 0, 0);
    aM1 = __builtin_amdgcn_mfma_f32_32x32x16_f16(a1, bh, aM1, 0, 0, 0);
    aL0 = __builtin_amdgcn_mfma_f32_32x32x16_f16(a0, bl, aL0, 0, 0, 0);
    aL0 = __builtin_amdgcn_mfma_f32_32x32x16_f16(l0, bh, aL0, 0, 0, 0);
    aL1 = __builtin_amdgcn_mfma_f32_32x32x16_f16(a1, bl, aL1, 0, 0, 0);
    aL1 = __builtin_amdgcn_mfma_f32_32x32x16_f16(l1, bh, aL1, 0, 0, 0);
  }

  {
    const int l = lane & 31;
    const int rbase = 4 * (lane >> 5);
#pragma unroll
    for (int reg = 0; reg < 16; ++reg) {
      const int row = (reg & 3) + 8 * (reg >> 2) + rbase;
      cand[wv][row][l] = aM0[reg] + aL0[reg] * INV2048;
      cand[wv][row + 32][l] = aM1[reg] + aL1[reg] * INV2048;
    }
  }
  __syncthreads();
  const int bn0 = ng * 128;
#pragma unroll
  for (int i = 0; i < 8; ++i) {
    const int idx = i * 256 + tid;
    const int b4 = (idx & 15) * 4;
    const int nl = idx >> 4;
    const float bi = b_ih[bn0 + nl];
    float4 o;
    o.x = cand[nl >> 5][b4 + 0][nl & 31] + bi;
    o.y = cand[nl >> 5][b4 + 1][nl & 31] + bi;
    o.z = cand[nl >> 5][b4 + 2][nl & 31] + bi;
    o.w = cand[nl >> 5][b4 + 3][nl & 31] + bi;
    *reinterpret_cast<float4*>(&Gi[((long long)s * (3 * H_) + bn0 + nl) * 64 + b4]) = o;
  }
}

// ---------------------------------------------------------------------------
// hh pre-activations via MFMA: preH[n][b] = h[b,:] . W_hh[n,:]. grid=96x256.
// ---------------------------------------------------------------------------
__global__ __launch_bounds__(256) void k_hh_mfma(
    const f16* __restrict__ Ahi, const f16* __restrict__ Alo,
    const f16* __restrict__ Bhi, const f16* __restrict__ Blo,
    float* __restrict__ preH)
{
  __shared__ float cand[4][64][33];
  const int tid = threadIdx.x;
  const int lane = tid & 63;
  const int wv = __builtin_amdgcn_readfirstlane(tid >> 6);
  const int nt = blockIdx.x;

  f32x16 aM0, aM1, aL0, aL1;
#pragma unroll
  for (int i = 0; i < 16; ++i) { aM0[i] = 0.f; aM1[i] = 0.f; aL0[i] = 0.f; aL1[i] = 0.f; }

  const f16x8* pB_h = reinterpret_cast<const f16x8*>(Bhi) + ((long long)nt * 64 + wv * 16) * 64 + lane;
  const f16x8* pB_l = reinterpret_cast<const f16x8*>(Blo) + ((long long)nt * 64 + wv * 16) * 64 + lane;
  const f16x8* pA_h = reinterpret_cast<const f16x8*>(Ahi) + (long long)(wv * 16) * 64 + lane;
  const f16x8* pA_l = reinterpret_cast<const f16x8*>(Alo) + (long long)(wv * 16) * 64 + lane;

#pragma unroll 4
  for (int q = 0; q < 16; ++q) {
    const int o = q * 64;
    f16x8 bh = pB_h[o];
    f16x8 bl = pB_l[o];
    f16x8 a0 = pA_h[o];
    f16x8 a1 = pA_h[o + 4096];
    f16x8 l0 = pA_l[o];
    f16x8 l1 = pA_l[o + 4096];
    aM0 = __builtin_amdgcn_mfma_f32_32x32x16_f16(a0, bh, aM0, 0, 0, 0);
    aM1 = __builtin_amdgcn_mfma_f32_32x32x16_f16(a1, bh, aM1, 0, 0, 0);
    aL0 = __builtin_amdgcn_mfma_f32_32x32x16_f16(a0, bl, aL0, 0, 0, 0);
    aL0 = __builtin_amdgcn_mfma_f32_32x32x16_f16(l0, bh, aL0, 0, 0, 0);
    aL1 = __builtin_amdgcn_mfma_f32_32x32x16_f16(a1, bl, aL1, 0, 0, 0);
    aL1 = __builtin_amdgcn_mfma_f32_32x32x16_f16(l1, bh, aL1, 0, 0, 0);
  }

  {
    const int l = lane & 31;
    const int rbase = 4 * (lane >> 5);
#pragma unroll
    for (int reg = 0; reg < 16; ++reg) {
      const int row = (reg & 3) + 8 * (reg >> 2) + rbase;
      cand[wv][row][l] = aM0[reg] + aL0[reg] * INV2048;
      cand[wv][row + 32][l] = aM1[reg] + aL1[reg] * INV2048;
    }
  }
  __syncthreads();
#pragma unroll
  for (int i = 0; i < 8; ++i) {
    const int idx = i * 256 + tid;
    const int b = idx & 63;
    const int l = idx >> 6;
    const float v = cand[0][b][l] + cand[1][b][l] + cand[2][b][l] + cand[3][b][l];
    preH[((long long)nt * 32 + l) * 64 + b] = v;
  }
}

// ---------------------------------------------------------------------------
// Encoder apply: gates from preH + Gi_t. grid = 256 x 256.
// ---------------------------------------------------------------------------
__global__ __launch_bounds__(256) void k_apply_enc(
    const float* __restrict__ preH, const float* __restrict__ Gi_t,
    const float* __restrict__ b_hh,
    const float* __restrict__ hT_in, float* __restrict__ hT_out,
    f16* __restrict__ Aohi, f16* __restrict__ Aolo)
{
  const int idx = blockIdx.x * 256 + threadIdx.x;
  const int b = idx & 63;
  const int j = idx >> 6;
  const float gr = preH[(long long)j * 64 + b] + Gi_t[(long long)j * 64 + b] + b_hh[j];
  const float gz = preH[(long long)(H_ + j) * 64 + b] + Gi_t[(long long)(H_ + j) * 64 + b] + b_hh[H_ + j];
  const float gin = Gi_t[(long long)(2 * H_ + j) * 64 + b];
  const float ghn = preH[(long long)(2 * H_ + j) * 64 + b] + b_hh[2 * H_ + j];
  const float r = 1.f / (1.f + expf(-gr));
  const float z = 1.f / (1.f + expf(-gz));
  const float n = tanhf(fmaf(r, ghn, gin));
  const float hp = hT_in[(long long)j * 64 + b];
  const float hv = (1.f - z) * n + z * hp;
  hT_out[(long long)j * 64 + b] = hv;
  write_frag(Aohi, Aolo, b, j, hv);
}

// ---------------------------------------------------------------------------
// Decoder apply: read 64 folded argmax keys (keyPrev, 64B-padded), fp32 ih
// (K=512) from gathered E rows, apply gates with preH. grid = 256 x 1024.
// XMODE: 0 = zero input (t=0), 2 = tokens from keyPrev.
// ---------------------------------------------------------------------------
template <int XMODE>
__global__ __launch_bounds__(1024) void k_dec_apply(
    const float* __restrict__ E, const unsigned long long* __restrict__ keyPrev,
    const float* __restrict__ W_ih,
    const float* __restrict__ b_ih, const float* __restrict__ b_hh,
    const float* __restrict__ preH, const float* __restrict__ hT_in,
    float* __restrict__ hT_out, f16* __restrict__ Aohi, f16* __restrict__ Aolo)
{
  __shared__ float4 a_lds[64 * 64];
  __shared__ float red[12 * 3 * 64];
  __shared__ int toks[64];
  const int tid = threadIdx.x;
  const int lane = tid & 63;
  const int wv = __builtin_amdgcn_readfirstlane(tid >> 6);
  const int jj = wv & 3;
  const int ks = wv >> 2;
  const int j = blockIdx.x * 4 + jj;
  const int kf16 = tid & 63;
  const int msub = tid >> 6;

  float accR = 0.f, accZ = 0.f, accIN = 0.f;

  if constexpr (XMODE == 2) {
    if (tid < 64) {
      const unsigned long long kk = keyPrev[(long long)tid * 8];
      toks[tid] = (int)(0xFFFFFFFFu - (unsigned)(kk & 0xFFFFFFFFull));
    }
    __syncthreads();

    const float* wr = W_ih + (long long)j * D_;
    const float* wz = W_ih + (long long)(j + H_) * D_;
    const float* wn = W_ih + (long long)(j + 2 * H_) * D_;
    for (int c = 0; c < 2; ++c) {
      __syncthreads();
#pragma unroll
      for (int p = 0; p < 4; ++p) {
        const int m = p * 16 + msub;
        const long long tok = toks[m];
        float4 v = *reinterpret_cast<const float4*>(E + tok * D_ + c * 256 + kf16 * 4);
        a_lds[m * 64 + (kf16 ^ (m & 7))] = v;
      }
      __syncthreads();
#pragma unroll 4
      for (int q = 0; q < 16; ++q) {
        const int kf = ks * 16 + q;
        float4 a = a_lds[lane * 64 + (kf ^ (lane & 7))];
        float4 w0 = *reinterpret_cast<const float4*>(wr + c * 256 + kf * 4);
        float4 w1 = *reinterpret_cast<const float4*>(wz + c * 256 + kf * 4);
        float4 w2 = *reinterpret_cast<const float4*>(wn + c * 256 + kf * 4);
        accR = fmaf(w0.x, a.x, accR); accR = fmaf(w0.y, a.y, accR);
        accR = fmaf(w0.z, a.z, accR); accR = fmaf(w0.w, a.w, accR);
        accZ = fmaf(w1.x, a.x, accZ); accZ = fmaf(w1.y, a.y, accZ);
        accZ = fmaf(w1.z, a.z, accZ); accZ = fmaf(w1.w, a.w, accZ);
        accIN = fmaf(w2.x, a.x, accIN); accIN = fmaf(w2.y, a.y, accIN);
        accIN = fmaf(w2.z, a.z, accIN); accIN = fmaf(w2.w, a.w, accIN);
      }
    }
  }

  if (ks > 0) {
    float* rp = red + (((ks - 1) * 4 + jj) * 3) * 64 + lane;
    rp[0] = accR; rp[64] = accZ; rp[128] = accIN;
  }
  __syncthreads();
  if (ks == 0) {
#pragma unroll
    for (int t2 = 0; t2 < 3; ++t2) {
      const float* rp = red + ((t2 * 4 + jj) * 3) * 64 + lane;
      accR += rp[0]; accZ += rp[64]; accIN += rp[128];
    }
    const float gr = accR + preH[(long long)j * 64 + lane] + b_ih[j] + b_hh[j];
    const float gz = accZ + preH[(long long)(H_ + j) * 64 + lane] + b_ih[H_ + j] + b_hh[H_ + j];
    const float gin = accIN + b_ih[2 * H_ + j];
    const float ghn = preH[(long long)(2 * H_ + j) * 64 + lane] + b_hh[2 * H_ + j];
    const float r = 1.f / (1.f + expf(-gr));
    const float z = 1.f / (1.f + expf(-gz));
    const float n = tanhf(fmaf(r, ghn, gin));
    const float hp = hT_in[(long long)j * 64 + lane];
    const float hv = (1.f - z) * n + z * hp;
    hT_out[(long long)j * 64 + lane] = hv;
    write_frag(Aohi, Aolo, lane, j, hv);
  }
}

// ---------------------------------------------------------------------------
// Fused logits + next-step hh, worklist @ 2 blocks/CU (grid 512). 1096 units.
// Per-row argmax: block-local running max in LDS across its logits units,
// then ONE atomicMax per row per block into keyStep (64B-padded rows).
// ---------------------------------------------------------------------------
__global__ __launch_bounds__(256) void k_logits_hh(
    const f16* __restrict__ Ahi, const f16* __restrict__ Alo,
    const f16* __restrict__ WOhi, const f16* __restrict__ WOlo,
    const f16* __restrict__ WHhi, const f16* __restrict__ WHlo,
    const float* __restrict__ b_out, float* __restrict__ out,
    unsigned long long* __restrict__ keyStep, float* __restrict__ preH, int t)
{
  __shared__ float cand[4][64][33];
  __shared__ unsigned long long wbest[4][64];
  __shared__ unsigned long long lbest[64];
  const int tid = threadIdx.x;
  const int lane = tid & 63;
  const int wv = __builtin_amdgcn_readfirstlane(tid >> 6);
  const int kb = wv * 16 * 64;  // K-slice base (f16x8 units)
  const int l31 = lane & 31;
  const int rbase = 4 * (lane >> 5);

  if (tid < 64) lbest[tid] = 0ull;
  __syncthreads();

  for (int u = blockIdx.x; u < 1096; u += 512) {
    f32x16 aM0, aM1, aL0, aL1;
#pragma unroll
    for (int i = 0; i < 16; ++i) { aM0[i] = 0.f; aM1[i] = 0.f; aL0[i] = 0.f; aL1[i] = 0.f; }

    const bool isLog = (u < 1000);
    const int nt = isLog ? u : (u - 1000);
    const f16x8* pBh = reinterpret_cast<const f16x8*>(isLog ? WOhi : WHhi) + (long long)nt * 4096 + kb + lane;
    const f16x8* pBl = reinterpret_cast<const f16x8*>(isLog ? WOlo : WHlo) + (long long)nt * 4096 + kb + lane;
    const f16x8* pAh = reinterpret_cast<const f16x8*>(Ahi) + kb + lane;
    const f16x8* pAl = reinterpret_cast<const f16x8*>(Alo) + kb + lane;

    __builtin_amdgcn_s_setprio(1);
#pragma unroll 8
    for (int q = 0; q < 16; ++q) {
      const int o = q * 64;
      f16x8 bh = pBh[o];
      f16x8 bl = pBl[o];
      f16x8 a0 = pAh[o];
      f16x8 a1 = pAh[o + 4096];
      f16x8 l0 = pAl[o];
      f16x8 l1 = pAl[o + 4096];
      aM0 = __builtin_amdgcn_mfma_f32_32x32x16_f16(a0, bh, aM0, 0, 0, 0);
      aM1 = __builtin_amdgcn_mfma_f32_32x32x16_f16(a1, bh, aM1, 0, 0, 0);
      aL0 = __builtin_amdgcn_mfma_f32_32x32x16_f16(a0, bl, aL0, 0, 0, 0);
      aL0 = __builtin_amdgcn_mfma_f32_32x32x16_f16(l0, bh, aL0, 0, 0, 0);
      aL1 = __builtin_amdgcn_mfma_f32_32x32x16_f16(a1, bl, aL1, 0, 0, 0);
      aL1 = __builtin_amdgcn_mfma_f32_32x32x16_f16(l1, bh, aL1, 0, 0, 0);
    }
    __builtin_amdgcn_s_setprio(0);

    // K-slice partials -> LDS
#pragma unroll
    for (int reg = 0; reg < 16; ++reg) {
      const int row = (reg & 3) + 8 * (reg >> 2) + rbase;
      cand[wv][row][l31] = aM0[reg] + aL0[reg] * INV2048;
      cand[wv][row + 32][l31] = aM1[reg] + aL1[reg] * INV2048;
    }
    __syncthreads();

    if (isLog) {
      // combine + bias + coalesced NT store; finals kept in slice 0
#pragma unroll
      for (int i = 0; i < 8; ++i) {
        const int idx = i * 256 + tid;
        const int col = idx & 31;
        const int row = idx >> 5;  // batch row 0..63
        const int nn = nt * 32 + col;
        const float v = cand[0][row][col] + cand[1][row][col] + cand[2][row][col] +
                        cand[3][row][col] + b_out[nn];
        __builtin_nontemporal_store(v, &out[(long long)row * (T_ * (long long)V_) + (long long)t * V_ + nn]);
        cand[0][row][col] = v;
      }
      __syncthreads();
      // per-row argmax keys: quarter q scans 8 cols of row r
      {
        const int r = tid & 63;
        const int q = tid >> 6;
        unsigned long long kk = 0ull;
#pragma unroll
        for (int cc = 0; cc < 8; ++cc) {
          const int col = q * 8 + cc;
          const float v = cand[0][r][col];
          unsigned uu = __float_as_uint(v);
          uu = (uu & 0x80000000u) ? ~uu : (uu | 0x80000000u);
          const unsigned long long key = ((unsigned long long)uu << 32) |
              (unsigned long long)(0xFFFFFFFFu - (unsigned)(nt * 32 + col));
          if (key > kk) kk = key;
        }
        wbest[q][r] = kk;
      }
      __syncthreads();
      if (tid < 64) {
        unsigned long long kk = wbest[0][tid];
#pragma unroll
        for (int w = 1; w < 4; ++w) { const unsigned long long q = wbest[w][tid]; if (q > kk) kk = q; }
        if (kk > lbest[tid]) lbest[tid] = kk;
      }
      __syncthreads();
    } else {
      // hh combine -> preH (for next GRU step)
#pragma unroll
      for (int i = 0; i < 8; ++i) {
        const int idx = i * 256 + tid;
        const int b = idx & 63;
        const int l = idx >> 6;
        const float v = cand[0][b][l] + cand[1][b][l] + cand[2][b][l] + cand[3][b][l];
        preH[((long long)nt * 32 + l) * 64 + b] = v;
      }
      __syncthreads();
    }
  }

  // one atomic per row per block (64B-padded rows; order-independent)
  if (tid < 64) {
    const unsigned long long kk = lbest[tid];
    if (kk) atomicMax(&keyStep[(long long)tid * 8], kk);
  }
}

// ---------------------------------------------------------------------------
// mu / logvar / z from hT. grid = 64 x 256.
// ---------------------------------------------------------------------------
__global__ __launch_bounds__(256) void k_mu_lv_z(
    const float* __restrict__ hT, const float* __restrict__ W_mu, const float* __restrict__ b_mu,
    const float* __restrict__ W_lv, const float* __restrict__ b_lv,
    const float* __restrict__ eps, float* __restrict__ out_mu, float* __restrict__ out_lv,
    float* __restrict__ zT)
{
  const int lane = threadIdx.x & 63;
  const int wv = __builtin_amdgcn_readfirstlane(threadIdx.x >> 6);
  const int l = blockIdx.x * 4 + wv;
  const float* wm = W_mu + (long long)l * H_;
  const float* wl = W_lv + (long long)l * H_;
  float am = 0.f, av = 0.f;
#pragma unroll 8
  for (int k = 0; k < H_; ++k) {
    const float h = hT[k * 64 + lane];
    am = fmaf(wm[k], h, am);
    av = fmaf(wl[k], h, av);
  }
  const float mu = am + b_mu[l];
  const float lv = av + b_lv[l];
  out_mu[lane * L_ + l] = mu;
  out_lv[lane * L_ + l] = lv;
  zT[l * 64 + lane] = fmaf(eps[lane * L_ + l], expf(0.5f * lv), mu);
}

// ---------------------------------------------------------------------------
// h_dec0 = z @ W_proj.T + b_proj. grid = 256 x 256.
// ---------------------------------------------------------------------------
__global__ __launch_bounds__(256) void k_proj(
    const float* __restrict__ zT, const float* __restrict__ W_proj,
    const float* __restrict__ b_proj, float* __restrict__ hT0,
    f16* __restrict__ Aohi, f16* __restrict__ Aolo)
{
  const int lane = threadIdx.x & 63;
  const int wv = __builtin_amdgcn_readfirstlane(threadIdx.x >> 6);
  const int j = blockIdx.x * 4 + wv;
  const float* wr = W_proj + (long long)j * L_;
  float acc = 0.f;
#pragma unroll 8
  for (int k = 0; k < L_; ++k) acc = fmaf(wr[k], zT[k * 64 + lane], acc);
  const float hv = acc + b_proj[j];
  hT0[(long long)j * 64 + lane] = hv;
  write_frag(Aohi, Aolo, lane, j, hv);
}

// ---------------------------------------------------------------------------
extern "C" void kernel_launch(void* const* d_in, const int* in_sizes, int n_in,
                              void* d_out, int out_size, void* d_ws, size_t ws_size,
                              hipStream_t stream) {
  (void)in_sizes; (void)n_in; (void)out_size;
  const int*   x        = (const int*)d_in[0];
  const float* eps      = (const float*)d_in[1];
  const float* E        = (const float*)d_in[2];
  const float* W_ih_enc = (const float*)d_in[3];
  const float* W_hh_enc = (const float*)d_in[4];
  const float* b_ih_enc = (const float*)d_in[5];
  const float* b_hh_enc = (const float*)d_in[6];
  const float* W_mu     = (const float*)d_in[7];
  const float* b_mu     = (const float*)d_in[8];
  const float* W_lv     = (const float*)d_in[9];
  const float* b_lv     = (const float*)d_in[10];
  const float* W_proj   = (const float*)d_in[11];
  const float* b_proj   = (const float*)d_in[12];
  const float* W_ih_dec = (const float*)d_in[13];
  const float* W_hh_dec = (const float*)d_in[14];
  const float* b_ih_dec = (const float*)d_in[15];
  const float* b_hh_dec = (const float*)d_in[16];
  const float* W_out    = (const float*)d_in[17];
  const float* b_out    = (const float*)d_in[18];

  float* out = (float*)d_out;
  const long long OFF_MU = (long long)B_ * T_ * V_;
  const long long OFF_LV = OFF_MU + (long long)B_ * L_;

  // Workspace layout (float offsets)
  float* ws = (float*)d_ws;
  float* hA   = ws + 0;                // enc hT (in-place)
  float* dA   = ws + 65536;            // dec hT (in-place)
  float* zT   = ws + 131072;           // [256][64]
  unsigned long long* keyStep = (unsigned long long*)(ws + 147456);  // [64 steps][64 rows][8] u64 (64B-padded)
  float* preH = ws + 278528;           // [3072][64]
  f16* frAhi  = (f16*)(ws + 475136);   // h A-frags [2][64][64][8]
  f16* frAlo  = (f16*)(ws + 507904);
  f16* WHEhi  = (f16*)(ws + 540672);   // [96][64][64][8]
  f16* WHElo  = (f16*)(ws + 2113536);
  f16* WHDhi  = (f16*)(ws + 3686400);
  f16* WHDlo  = (f16*)(ws + 5259264);
  f16* WIEhi  = (f16*)(ws + 6832128);  // [96][32][64][8]
  f16* WIElo  = (f16*)(ws + 7618560);
  // overlay: {XAenc + Gi} (encoder) then {WO frags} (decoder)
  f16* XAhi   = (f16*)(ws + 8404992);  // [128][32][64][8]
  f16* XAlo   = (f16*)(ws + 9453568);
  float* Gi   = ws + 10502144;         // [64][3072][64]
  f16* WOhi   = (f16*)(ws + 8404992);  // [1000][64][64][8]
  f16* WOlo   = (f16*)(ws + 24788992);
  const size_t WS_NEED = (size_t)41172992 * 4;
  if (ws_size < WS_NEED) return;

  hipMemsetAsync(hA, 0, (size_t)H_ * B_ * sizeof(float), stream);
  hipMemsetAsync(frAhi, 0, (size_t)2 * 65536 * sizeof(f16), stream);   // frAhi+frAlo
  hipMemsetAsync(keyStep, 0, (size_t)T_ * 64 * 8 * 8, stream);         // 256 KB

  // ---- one-time weight packs ----
  k_pack_wf<1024><<<3 * H_, 256, 0, stream>>>(W_hh_enc, WHEhi, WHElo);
  k_pack_wf<1024><<<3 * H_, 256, 0, stream>>>(W_hh_dec, WHDhi, WHDlo);
  k_pack_wf<512><<<3 * H_, 128, 0, stream>>>(W_ih_enc, WIEhi, WIElo);
  k_pack_xe<<<S_ * B_, 128, 0, stream>>>(x, E, XAhi, XAlo);

  // ---- encoder input gates (one GEMM) ----
  k_gates_mfma<<<64 * 24, 256, 0, stream>>>(XAhi, XAlo, WIEhi, WIElo, b_ih_enc, Gi);

  // ---- encoder: 64 x (hh MFMA + apply) ----
  for (int t = 0; t < S_; ++t) {
    k_hh_mfma<<<96, 256, 0, stream>>>(frAhi, frAlo, WHEhi, WHElo, preH);
    k_apply_enc<<<256, 256, 0, stream>>>(preH, Gi + (long long)t * 3 * H_ * B_,
                                         b_hh_enc, hA, hA, frAhi, frAlo);
  }

  // ---- latent ----
  k_mu_lv_z<<<64, 256, 0, stream>>>(hA, W_mu, b_mu, W_lv, b_lv, eps,
                                    out + OFF_MU, out + OFF_LV, zT);
  k_proj<<<256, 256, 0, stream>>>(zT, W_proj, b_proj, dA, frAhi, frAlo);

  // ---- pack W_out (overwrites XA+Gi region — both dead now) ----
  k_pack_wf<1024><<<V_, 256, 0, stream>>>(W_out, WOhi, WOlo);

  // ---- initial decoder hh ----
  k_hh_mfma<<<96, 256, 0, stream>>>(frAhi, frAlo, WHDhi, WHDlo, preH);

  // ---- decoder: 64 x (apply + worklist logits/hh with atomic argmax) ----
  for (int t = 0; t < T_; ++t) {
    if (t == 0) {
      k_dec_apply<0><<<256, 1024, 0, stream>>>(
          E, nullptr, W_ih_dec, b_ih_dec, b_hh_dec, preH, dA, dA, frAhi, frAlo);
    } else {
      k_dec_apply<2><<<256, 1024, 0, stream>>>(
          E, keyStep + (long long)(t - 1) * 512, W_ih_dec, b_ih_dec, b_hh_dec,
          preH, dA, dA, frAhi, frAlo);
    }
    k_logits_hh<<<512, 256, 0, stream>>>(frAhi, frAlo, WOhi, WOlo, WHDhi, WHDlo,
                                         b_out, out, keyStep + (long long)t * 512, preH, t);
  }
}